// Round 1
// baseline (899.802 us; speedup 1.0000x reference)
//
#include <hip/hip_runtime.h>
#include <math.h>

#define PI_F 3.14159265358979323846f

// ---------------- wave reduce ----------------
__device__ __forceinline__ float wave_reduce_sum(float v) {
  v += __shfl_xor(v, 32, 64);
  v += __shfl_xor(v, 16, 64);
  v += __shfl_xor(v, 8, 64);
  v += __shfl_xor(v, 4, 64);
  v += __shfl_xor(v, 2, 64);
  v += __shfl_xor(v, 1, 64);
  return v;
}

// ---------------- LayerNorm: one 64-lane wave per token (C=192) ----------------
__global__ __launch_bounds__(64) void ln_kernel(const float* __restrict__ x,
    const float* __restrict__ w, const float* __restrict__ b, float* __restrict__ o) {
  int row = blockIdx.x;
  int lane = threadIdx.x;
  const float* xr = x + row * 192;
  float v0 = xr[lane], v1 = xr[lane + 64], v2 = xr[lane + 128];
  float s  = wave_reduce_sum(v0 + v1 + v2);
  float s2 = wave_reduce_sum(v0 * v0 + v1 * v1 + v2 * v2);
  float mu  = s * (1.f / 192.f);
  float var = s2 * (1.f / 192.f) - mu * mu;
  float rs  = rsqrtf(var + 1e-5f);
  float* orow = o + row * 192;
  orow[lane]       = (v0 - mu) * rs * w[lane]       + b[lane];
  orow[lane + 64]  = (v1 - mu) * rs * w[lane + 64]  + b[lane + 64];
  orow[lane + 128] = (v2 - mu) * rs * w[lane + 128] + b[lane + 128];
}

// ---------------- tiled GEMM: C[m,n] = sum_k A[m,k]*W[n,k] (+res) ----------------
// A:[M,K] row-major, W:[N,K] row-major. BM=BN=64, BK=32, 256 thr, 4x4 micro.
__global__ __launch_bounds__(256) void gemm_tn(const float* __restrict__ A,
    const float* __restrict__ W, const float* __restrict__ res, float* __restrict__ C,
    int M, int N, int K) {
  __shared__ float As[64][33];   // [m][k], pad breaks 4-way bank conflict
  __shared__ float Ws[32][65];   // [k][n], pad makes writes conflict-free
  int tid = threadIdx.x;
  int m0 = blockIdx.y * 64, n0 = blockIdx.x * 64;
  int tr = tid >> 4, tc = tid & 15;
  float acc[4][4] = {{0.f}};
  for (int kk = 0; kk < K; kk += 32) {
    for (int i = tid; i < 64 * 32; i += 256) {
      int m = i >> 5, k = i & 31;
      As[m][k] = A[(m0 + m) * K + kk + k];
      float v = 0.f;
      if (n0 + m < N) v = W[(n0 + m) * K + kk + k];
      Ws[k][m] = v;
    }
    __syncthreads();
#pragma unroll
    for (int k = 0; k < 32; ++k) {
      float a[4], bb[4];
#pragma unroll
      for (int i = 0; i < 4; ++i) a[i] = As[tr * 4 + i][k];
#pragma unroll
      for (int j = 0; j < 4; ++j) bb[j] = Ws[k][tc * 4 + j];
#pragma unroll
      for (int i = 0; i < 4; ++i)
#pragma unroll
        for (int j = 0; j < 4; ++j)
          acc[i][j] = fmaf(a[i], bb[j], acc[i][j]);
    }
    __syncthreads();
  }
#pragma unroll
  for (int i = 0; i < 4; ++i) {
    int m = m0 + tr * 4 + i;
#pragma unroll
    for (int j = 0; j < 4; ++j) {
      int n = n0 + tc * 4 + j;
      if (n < N) {
        float v = acc[i][j];
        if (res) v += res[m * N + n];
        C[m * N + n] = v;
      }
    }
  }
}

// ---------------- causal depthwise conv1d(k=4) + SiLU ----------------
// xm = xz[:, :384]; xc[b,t,d] = silu(sum_j xm[b,t-3+j,d]*cw[d,j] + cb[d])
__global__ __launch_bounds__(256) void conv_silu(const float* __restrict__ xz,
    const float* __restrict__ cw, const float* __restrict__ cb, float* __restrict__ xc) {
  int e = blockIdx.x * 256 + threadIdx.x;
  if (e >= 4 * 1024 * 384) return;
  int d = e % 384;
  int t = (e / 384) % 1024;
  int b = e / (384 * 1024);
  const float* base = xz + (size_t)(b * 1024) * 768 + d;
  float acc = cb[d];
#pragma unroll
  for (int j = 0; j < 4; ++j) {
    int tt = t - 3 + j;
    if (tt >= 0) acc += base[(size_t)tt * 768] * cw[d * 4 + j];
  }
  float sg = 1.f / (1.f + __expf(-acc));
  xc[e] = acc * sg;
}

// ---------------- delta = softplus(dt @ dt_proj_w^T + bias) ----------------
__global__ __launch_bounds__(256) void delta_kernel(const float* __restrict__ dbc,
    const float* __restrict__ dtw, const float* __restrict__ dtb, float* __restrict__ dlt) {
  int e = blockIdx.x * 256 + threadIdx.x;
  if (e >= 4096 * 384) return;
  int d = e % 384;
  int t = e / 384;
  float s = dtb[d];
  const float* dtv = dbc + t * 140;
#pragma unroll
  for (int r = 0; r < 12; ++r) s += dtv[r] * dtw[d * 12 + r];
  dlt[e] = (s > 20.f) ? s : log1pf(__expf(s));
}

// ---------------- selective scan: one wave per (b,d), lane = state n ----------------
__global__ __launch_bounds__(256) void scan_kernel(const float* __restrict__ dlt,
    const float* __restrict__ xc, const float* __restrict__ dbc,
    const float* __restrict__ A_log, float* __restrict__ y) {
  int wave = (blockIdx.x * 256 + threadIdx.x) >> 6;  // [0,1536)
  int lane = threadIdx.x & 63;
  int b = wave / 384, d = wave % 384;
  float A = -__expf(A_log[d * 64 + lane]);
  float h = 0.f;
  const float* dbcB = dbc + (size_t)b * 1024 * 140 + 12 + lane;
  const float* dbcC = dbc + (size_t)b * 1024 * 140 + 76 + lane;
  const float* dp   = dlt + (size_t)b * 1024 * 384 + d;
  const float* xp   = xc  + (size_t)b * 1024 * 384 + d;
  float* yp         = y   + (size_t)b * 1024 * 384 + d;
  float dv = dp[0], xv = xp[0], Bv = dbcB[0], Cv = dbcC[0];
  for (int t = 0; t < 1024; ++t) {
    int tn = (t < 1023) ? t + 1 : 1023;
    float dv_n = dp[(size_t)tn * 384];
    float xv_n = xp[(size_t)tn * 384];
    float Bv_n = dbcB[(size_t)tn * 140];
    float Cv_n = dbcC[(size_t)tn * 140];
    float dA = __expf(dv * A);
    h = fmaf(h, dA, (dv * xv) * Bv);
    float p = wave_reduce_sum(h * Cv);
    if (lane == 0) yp[(size_t)t * 384] = p;
    dv = dv_n; xv = xv_n; Bv = Bv_n; Cv = Cv_n;
  }
}

// ---------------- gating: yg = (y + xc*D) * silu(z), in-place on y ----------------
__global__ __launch_bounds__(256) void gate_kernel(float* __restrict__ y,
    const float* __restrict__ xc, const float* __restrict__ xz,
    const float* __restrict__ D, float* __restrict__ yg) {
  int e = blockIdx.x * 256 + threadIdx.x;
  if (e >= 4096 * 384) return;
  int d = e % 384;
  int row = e / 384;
  float zv = xz[(size_t)row * 768 + 384 + d];
  float sg = zv / (1.f + __expf(-zv));
  yg[e] = (y[e] + xc[e] * D[d]) * sg;
}

// ---------------- 1024-pt radix-2 FFT on 4 LDS columns ----------------
__device__ void fft1024(float (*re)[1024], float (*im)[1024], int tid, float sgn) {
  for (int idx = tid; idx < 4096; idx += 256) {
    int c = idx >> 10, i = idx & 1023;
    int r = (int)(__brev((unsigned)i) >> 22);
    if (i < r) {
      float tr = re[c][i]; re[c][i] = re[c][r]; re[c][r] = tr;
      float ti = im[c][i]; im[c][i] = im[c][r]; im[c][r] = ti;
    }
  }
  __syncthreads();
  for (int s = 0; s < 10; ++s) {
    int half = 1 << s;
    for (int u = tid; u < 2048; u += 256) {
      int c = u >> 9, v = u & 511;
      int j = v & (half - 1);
      int i0 = ((v >> s) << (s + 1)) + j;
      int i1 = i0 + half;
      float ang = sgn * PI_F * (float)j / (float)half;
      float sw, cw;
      __sincosf(ang, &sw, &cw);
      float br = re[c][i1], bi = im[c][i1];
      float tr = br * cw - bi * sw;
      float ti = br * sw + bi * cw;
      float ar = re[c][i0], ai = im[c][i0];
      re[c][i1] = ar - tr; im[c][i1] = ai - ti;
      re[c][i0] = ar + tr; im[c][i0] = ai + ti;
    }
    __syncthreads();
  }
}

// forward fft2 (block-axis 4-pt DFT + 1024-pt FFT), one wg per (B,d)
__global__ __launch_bounds__(256) void fft_fwd(const float* __restrict__ xin,
    float* __restrict__ Xre, float* __restrict__ Xim) {
  __shared__ float re[4][1024];
  __shared__ float im[4][1024];
  int Bi = blockIdx.x / 48, d = blockIdx.x % 48;
  int tid = threadIdx.x;
  for (int n = tid; n < 1024; n += 256) {
    const float* p = xin + (size_t)(Bi * 1024 + n) * 192 + d;
    float v0 = p[0], v1 = p[48], v2 = p[96], v3 = p[144];
    float s02 = v0 + v2, d02 = v0 - v2, s13 = v1 + v3, d13 = v1 - v3;
    re[0][n] = s02 + s13; im[0][n] = 0.f;
    re[1][n] = d02;       im[1][n] = -d13;
    re[2][n] = s02 - s13; im[2][n] = 0.f;
    re[3][n] = d02;       im[3][n] = d13;
  }
  __syncthreads();
  fft1024(re, im, tid, -1.0f);
  for (int idx = tid; idx < 4096; idx += 256) {
    int c = idx >> 10, k = idx & 1023;
    size_t o = ((size_t)(Bi * 1024 + k) * 4 + c) * 48 + d;
    Xre[o] = re[c][k] * (1.f / 64.f);
    Xim[o] = im[c][k] * (1.f / 64.f);
  }
}

// weight transpose: [p][b][d][k] -> [p][b][k][d] (for contiguous per-output rows)
__global__ __launch_bounds__(256) void wtrans(const float* __restrict__ src,
    float* __restrict__ dst) {
  int e = blockIdx.x * 256 + threadIdx.x;
  if (e >= 18432) return;
  int kk = e % 48;
  int dd = (e / 48) % 48;
  int pb = e / 2304;
  dst[pb * 2304 + kk * 48 + dd] = src[pb * 2304 + dd * 48 + kk];
}

// frequency-domain 2-layer complex block matmul + relu + softshrink (in-place on X)
__global__ __launch_bounds__(64) void einfft_mix(float* __restrict__ Xre,
    float* __restrict__ Xim, const float* __restrict__ t1, const float* __restrict__ t2,
    const float* __restrict__ cb1, const float* __restrict__ cb2) {
  __shared__ float r1s[64 * 49];
  __shared__ float i1s[64 * 49];
  int blk = blockIdx.x;
  int Bi = blk >> 6;
  int b  = (blk >> 4) & 3;
  int lane = threadIdx.x;
  int k = ((blk & 15) << 6) + lane;
  const float* w1r = t1 + b * 2304;
  const float* w1i = t1 + 9216 + b * 2304;
  const float* w2r = t2 + b * 2304;
  const float* w2i = t2 + 9216 + b * 2304;
  const float* b1r = cb1 + b * 48;
  const float* b1i = cb1 + 192 + b * 48;
  const float* b2r = cb2 + b * 48;
  const float* b2i = cb2 + 192 + b * 48;
  size_t base = ((size_t)(Bi * 1024 + k) * 4 + b) * 48;
  float Xr[48], Xi[48];
  const float4* pr = reinterpret_cast<const float4*>(Xre + base);
  const float4* pi = reinterpret_cast<const float4*>(Xim + base);
#pragma unroll
  for (int q = 0; q < 12; ++q) {
    float4 vr = pr[q], vi = pi[q];
    Xr[4 * q + 0] = vr.x; Xr[4 * q + 1] = vr.y; Xr[4 * q + 2] = vr.z; Xr[4 * q + 3] = vr.w;
    Xi[4 * q + 0] = vi.x; Xi[4 * q + 1] = vi.y; Xi[4 * q + 2] = vi.z; Xi[4 * q + 3] = vi.w;
  }
  for (int j = 0; j < 48; ++j) {
    float ar = b1r[j], ai = b1i[j];
    const float* wr = w1r + j * 48;
    const float* wi = w1i + j * 48;
#pragma unroll
    for (int dd = 0; dd < 48; ++dd) {
      ar += Xr[dd] * wr[dd] - Xi[dd] * wi[dd];
      ai += Xr[dd] * wi[dd] + Xi[dd] * wr[dd];
    }
    r1s[lane * 49 + j] = fmaxf(ar, 0.f);
    i1s[lane * 49 + j] = fmaxf(ai, 0.f);
  }
  for (int j = 0; j < 48; ++j) {
    float ar = b2r[j], ai = b2i[j];
    const float* wr = w2r + j * 48;
    const float* wi = w2i + j * 48;
#pragma unroll
    for (int dd = 0; dd < 48; ++dd) {
      float rv = r1s[lane * 49 + dd], iv = i1s[lane * 49 + dd];
      ar += rv * wr[dd] - iv * wi[dd];
      ai += rv * wi[dd] + iv * wr[dd];
    }
    float zr = (ar > 0.01f) ? ar - 0.01f : ((ar < -0.01f) ? ar + 0.01f : 0.f);
    float zi = (ai > 0.01f) ? ai - 0.01f : ((ai < -0.01f) ? ai + 0.01f : 0.f);
    Xre[base + j] = zr;
    Xim[base + j] = zi;
  }
}

// inverse fft2 + take real + residual add -> final output
__global__ __launch_bounds__(256) void fft_inv(const float* __restrict__ Zre,
    const float* __restrict__ Zim, const float* __restrict__ x1, float* __restrict__ out) {
  __shared__ float re[4][1024];
  __shared__ float im[4][1024];
  int Bi = blockIdx.x / 48, d = blockIdx.x % 48;
  int tid = threadIdx.x;
  for (int idx = tid; idx < 4096; idx += 256) {
    int c = idx >> 10, k = idx & 1023;
    size_t o = ((size_t)(Bi * 1024 + k) * 4 + c) * 48 + d;
    re[c][k] = Zre[o];
    im[c][k] = Zim[o];
  }
  __syncthreads();
  fft1024(re, im, tid, 1.0f);
  for (int n = tid; n < 1024; n += 256) {
    float r0 = re[0][n], r1 = re[1][n], r2 = re[2][n], r3 = re[3][n];
    float i1 = im[1][n], i3 = im[3][n];
    float y0 = r0 + r1 + r2 + r3;
    float y1 = r0 - i1 - r2 + i3;
    float y2 = r0 - r1 + r2 - r3;
    float y3 = r0 + i1 - r2 - i3;
    size_t base = (size_t)(Bi * 1024 + n) * 192 + d;
    out[base]       = x1[base]       + y0 * (1.f / 64.f);
    out[base + 48]  = x1[base + 48]  + y1 * (1.f / 64.f);
    out[base + 96]  = x1[base + 96]  + y2 * (1.f / 64.f);
    out[base + 144] = x1[base + 144] + y3 * (1.f / 64.f);
  }
}

extern "C" void kernel_launch(void* const* d_in, const int* in_sizes, int n_in,
                              void* d_out, int out_size, void* d_ws, size_t ws_size,
                              hipStream_t stream) {
  const float* x         = (const float*)d_in[0];
  const float* ln1_w     = (const float*)d_in[1];
  const float* ln1_b     = (const float*)d_in[2];
  const float* in_proj_w = (const float*)d_in[3];
  const float* conv_w    = (const float*)d_in[4];
  const float* conv_b    = (const float*)d_in[5];
  const float* x_proj_w  = (const float*)d_in[6];
  const float* dt_proj_w = (const float*)d_in[7];
  const float* dt_proj_b = (const float*)d_in[8];
  const float* A_log     = (const float*)d_in[9];
  const float* Dvec      = (const float*)d_in[10];
  const float* out_proj_w= (const float*)d_in[11];
  const float* ln2_w     = (const float*)d_in[12];
  const float* ln2_b     = (const float*)d_in[13];
  const float* cw1       = (const float*)d_in[14];
  const float* cw2       = (const float*)d_in[15];
  const float* cb1       = (const float*)d_in[16];
  const float* cb2       = (const float*)d_in[17];
  float* out = (float*)d_out;
  float* ws  = (float*)d_ws;

  // workspace layout (floats); xln reused as x1 after in_proj consumes it
  float* xln = ws;                       // 786432
  float* xz  = xln + 786432;             // 3145728
  float* xc  = xz  + 3145728;            // 1572864
  float* dbc = xc  + 1572864;            // 573440
  float* dlt = dbc + 573440;             // 1572864
  float* yv  = dlt + 1572864;            // 1572864 (gated in-place)
  float* x2  = yv  + 1572864;            // 786432
  float* Xre = x2  + 786432;             // 786432 (Z written in-place)
  float* Xim = Xre + 786432;             // 786432
  float* t1  = Xim + 786432;             // 18432
  float* t2  = t1  + 18432;              // 18432  -> total ~46.5 MB

  ln_kernel<<<4096, 64, 0, stream>>>(x, ln1_w, ln1_b, xln);
  gemm_tn<<<dim3(12, 64), 256, 0, stream>>>(xln, in_proj_w, nullptr, xz, 4096, 768, 192);
  conv_silu<<<6144, 256, 0, stream>>>(xz, conv_w, conv_b, xc);
  gemm_tn<<<dim3(3, 64), 256, 0, stream>>>(xc, x_proj_w, nullptr, dbc, 4096, 140, 384);
  delta_kernel<<<6144, 256, 0, stream>>>(dbc, dt_proj_w, dt_proj_b, dlt);
  scan_kernel<<<384, 256, 0, stream>>>(dlt, xc, dbc, A_log, yv);
  gate_kernel<<<6144, 256, 0, stream>>>(yv, xc, xz, Dvec, yv);
  float* x1 = xln;
  gemm_tn<<<dim3(3, 64), 256, 0, stream>>>(yv, out_proj_w, x, x1, 4096, 192, 384);
  ln_kernel<<<4096, 64, 0, stream>>>(x1, ln2_w, ln2_b, x2);
  fft_fwd<<<192, 256, 0, stream>>>(x2, Xre, Xim);
  wtrans<<<72, 256, 0, stream>>>(cw1, t1);
  wtrans<<<72, 256, 0, stream>>>(cw2, t2);
  einfft_mix<<<256, 64, 0, stream>>>(Xre, Xim, t1, t2, cb1, cb2);
  fft_inv<<<192, 256, 0, stream>>>(Xre, Xim, x1, out);
}

// Round 2
// 698.938 us; speedup vs baseline: 1.2874x; 1.2874x over previous
//
#include <hip/hip_runtime.h>
#include <math.h>

#define PI_F 3.14159265358979323846f

// ---------------- wave reduce ----------------
__device__ __forceinline__ float wave_reduce_sum(float v) {
  v += __shfl_xor(v, 32, 64);
  v += __shfl_xor(v, 16, 64);
  v += __shfl_xor(v, 8, 64);
  v += __shfl_xor(v, 4, 64);
  v += __shfl_xor(v, 2, 64);
  v += __shfl_xor(v, 1, 64);
  return v;
}

// ---------------- LayerNorm: one 64-lane wave per token (C=192) ----------------
__global__ __launch_bounds__(64) void ln_kernel(const float* __restrict__ x,
    const float* __restrict__ w, const float* __restrict__ b, float* __restrict__ o) {
  int row = blockIdx.x;
  int lane = threadIdx.x;
  const float* xr = x + row * 192;
  float v0 = xr[lane], v1 = xr[lane + 64], v2 = xr[lane + 128];
  float s  = wave_reduce_sum(v0 + v1 + v2);
  float s2 = wave_reduce_sum(v0 * v0 + v1 * v1 + v2 * v2);
  float mu  = s * (1.f / 192.f);
  float var = s2 * (1.f / 192.f) - mu * mu;
  float rs  = rsqrtf(var + 1e-5f);
  float* orow = o + row * 192;
  orow[lane]       = (v0 - mu) * rs * w[lane]       + b[lane];
  orow[lane + 64]  = (v1 - mu) * rs * w[lane + 64]  + b[lane + 64];
  orow[lane + 128] = (v2 - mu) * rs * w[lane + 128] + b[lane + 128];
}

// ---------------- tiled GEMM: C[m,n] = sum_k A[m,k]*W[n,k] (+res) ----------------
__global__ __launch_bounds__(256) void gemm_tn(const float* __restrict__ A,
    const float* __restrict__ W, const float* __restrict__ res, float* __restrict__ C,
    int M, int N, int K) {
  __shared__ float As[64][33];
  __shared__ float Ws[32][65];
  int tid = threadIdx.x;
  int m0 = blockIdx.y * 64, n0 = blockIdx.x * 64;
  int tr = tid >> 4, tc = tid & 15;
  float acc[4][4] = {{0.f}};
  for (int kk = 0; kk < K; kk += 32) {
    for (int i = tid; i < 64 * 32; i += 256) {
      int m = i >> 5, k = i & 31;
      As[m][k] = A[(m0 + m) * K + kk + k];
      float v = 0.f;
      if (n0 + m < N) v = W[(n0 + m) * K + kk + k];
      Ws[k][m] = v;
    }
    __syncthreads();
#pragma unroll
    for (int k = 0; k < 32; ++k) {
      float a[4], bb[4];
#pragma unroll
      for (int i = 0; i < 4; ++i) a[i] = As[tr * 4 + i][k];
#pragma unroll
      for (int j = 0; j < 4; ++j) bb[j] = Ws[k][tc * 4 + j];
#pragma unroll
      for (int i = 0; i < 4; ++i)
#pragma unroll
        for (int j = 0; j < 4; ++j)
          acc[i][j] = fmaf(a[i], bb[j], acc[i][j]);
    }
    __syncthreads();
  }
#pragma unroll
  for (int i = 0; i < 4; ++i) {
    int m = m0 + tr * 4 + i;
#pragma unroll
    for (int j = 0; j < 4; ++j) {
      int n = n0 + tc * 4 + j;
      if (n < N) {
        float v = acc[i][j];
        if (res) v += res[m * N + n];
        C[m * N + n] = v;
      }
    }
  }
}

// ---------------- causal depthwise conv1d(k=4) + SiLU ----------------
__global__ __launch_bounds__(256) void conv_silu(const float* __restrict__ xz,
    const float* __restrict__ cw, const float* __restrict__ cb, float* __restrict__ xc) {
  int e = blockIdx.x * 256 + threadIdx.x;
  if (e >= 4 * 1024 * 384) return;
  int d = e % 384;
  int t = (e / 384) % 1024;
  int b = e / (384 * 1024);
  const float* base = xz + (size_t)(b * 1024) * 768 + d;
  float acc = cb[d];
#pragma unroll
  for (int j = 0; j < 4; ++j) {
    int tt = t - 3 + j;
    if (tt >= 0) acc += base[(size_t)tt * 768] * cw[d * 4 + j];
  }
  float sg = 1.f / (1.f + __expf(-acc));
  xc[e] = acc * sg;
}

// ---------------- delta = softplus(dt @ dt_proj_w^T + bias) ----------------
__global__ __launch_bounds__(256) void delta_kernel(const float* __restrict__ dbc,
    const float* __restrict__ dtw, const float* __restrict__ dtb, float* __restrict__ dlt) {
  int e = blockIdx.x * 256 + threadIdx.x;
  if (e >= 4096 * 384) return;
  int d = e % 384;
  int t = e / 384;
  float s = dtb[d];
  const float* dtv = dbc + t * 140;
#pragma unroll
  for (int r = 0; r < 12; ++r) s += dtv[r] * dtw[d * 12 + r];
  dlt[e] = (s > 20.f) ? s : log1pf(__expf(s));
}

// ---------------- chunked selective scan ----------------
// recurrence per (b,d,n): h_t = a_t*h_{t-1} + b_t, a_t = exp(delta*A),
// b_t = delta*x*B. 8 chunks x 128 steps; pass1: chunk summaries (P,S);
// pass2: sequential combine -> per-chunk h_init; pass3: local replay + y.

// pass 1: one wave per (b,d,chunk); lane = state n
__global__ __launch_bounds__(256) void scan_p1(const float* __restrict__ dlt,
    const float* __restrict__ xc, const float* __restrict__ dbc,
    const float* __restrict__ A_log, float* __restrict__ P, float* __restrict__ S) {
  int gw = (blockIdx.x * 256 + threadIdx.x) >> 6;  // [0, 12288)
  int lane = threadIdx.x & 63;
  int c  = gw & 7;
  int bd = gw >> 3;
  int b = bd / 384, d = bd % 384;
  float A = -__expf(A_log[d * 64 + lane]);
  int t0 = c * 128;
  const float* dp = dlt + ((size_t)b * 1024 + t0) * 384 + d;
  const float* xp = xc  + ((size_t)b * 1024 + t0) * 384 + d;
  const float* Bp = dbc + ((size_t)b * 1024 + t0) * 140 + 12 + lane;
  float Pv = 1.f, Sv = 0.f;
#pragma unroll 4
  for (int t = 0; t < 128; ++t) {
    float dv = dp[(size_t)t * 384];
    float xv = xp[(size_t)t * 384];
    float Bv = Bp[(size_t)t * 140];
    float a = __expf(dv * A);
    Pv *= a;
    Sv = fmaf(Sv, a, dv * xv * Bv);
  }
  size_t o = (size_t)gw * 64 + lane;   // layout [bd][c][n]
  P[o] = Pv;
  S[o] = Sv;
}

// pass 2: one wave per (b,d); sequential over 8 chunks
__global__ __launch_bounds__(256) void scan_p2(const float* __restrict__ P,
    const float* __restrict__ S, float* __restrict__ Hi) {
  int bd = (blockIdx.x * 256 + threadIdx.x) >> 6;  // [0, 1536)
  int lane = threadIdx.x & 63;
  size_t base = (size_t)bd * 8 * 64 + lane;
  float H = 0.f;
  Hi[base] = 0.f;
#pragma unroll
  for (int c = 1; c < 8; ++c) {
    float Pv = P[base + (size_t)(c - 1) * 64];
    float Sv = S[base + (size_t)(c - 1) * 64];
    H = fmaf(Pv, H, Sv);
    Hi[base + (size_t)c * 64] = H;
  }
}

// pass 3: one wave per (b,d,chunk); replay 128 steps from h_init, emit y
__global__ __launch_bounds__(256) void scan_p3(const float* __restrict__ dlt,
    const float* __restrict__ xc, const float* __restrict__ dbc,
    const float* __restrict__ A_log, const float* __restrict__ Hi,
    float* __restrict__ y) {
  int gw = (blockIdx.x * 256 + threadIdx.x) >> 6;
  int lane = threadIdx.x & 63;
  int c  = gw & 7;
  int bd = gw >> 3;
  int b = bd / 384, d = bd % 384;
  float A = -__expf(A_log[d * 64 + lane]);
  int t0 = c * 128;
  const float* dp = dlt + ((size_t)b * 1024 + t0) * 384 + d;
  const float* xp = xc  + ((size_t)b * 1024 + t0) * 384 + d;
  const float* Bp = dbc + ((size_t)b * 1024 + t0) * 140 + 12 + lane;
  const float* Cp = dbc + ((size_t)b * 1024 + t0) * 140 + 76 + lane;
  float* yp = y + ((size_t)b * 1024 + t0) * 384 + d;
  float h = Hi[(size_t)gw * 64 + lane];
#pragma unroll 2
  for (int t = 0; t < 128; ++t) {
    float dv = dp[(size_t)t * 384];
    float xv = xp[(size_t)t * 384];
    float Bv = Bp[(size_t)t * 140];
    float Cv = Cp[(size_t)t * 140];
    float a = __expf(dv * A);
    h = fmaf(h, a, dv * xv * Bv);
    float p = wave_reduce_sum(h * Cv);
    if (lane == 0) yp[(size_t)t * 384] = p;
  }
}

// ---------------- gating: yg = (y + xc*D) * silu(z) ----------------
__global__ __launch_bounds__(256) void gate_kernel(float* __restrict__ y,
    const float* __restrict__ xc, const float* __restrict__ xz,
    const float* __restrict__ D, float* __restrict__ yg) {
  int e = blockIdx.x * 256 + threadIdx.x;
  if (e >= 4096 * 384) return;
  int d = e % 384;
  int row = e / 384;
  float zv = xz[(size_t)row * 768 + 384 + d];
  float sg = zv / (1.f + __expf(-zv));
  yg[e] = (y[e] + xc[e] * D[d]) * sg;
}

// ---------------- 1024-pt radix-2 FFT on 4 LDS columns ----------------
__device__ void fft1024(float (*re)[1024], float (*im)[1024], int tid, float sgn) {
  for (int idx = tid; idx < 4096; idx += 256) {
    int c = idx >> 10, i = idx & 1023;
    int r = (int)(__brev((unsigned)i) >> 22);
    if (i < r) {
      float tr = re[c][i]; re[c][i] = re[c][r]; re[c][r] = tr;
      float ti = im[c][i]; im[c][i] = im[c][r]; im[c][r] = ti;
    }
  }
  __syncthreads();
  for (int s = 0; s < 10; ++s) {
    int half = 1 << s;
    for (int u = tid; u < 2048; u += 256) {
      int c = u >> 9, v = u & 511;
      int j = v & (half - 1);
      int i0 = ((v >> s) << (s + 1)) + j;
      int i1 = i0 + half;
      float ang = sgn * PI_F * (float)j / (float)half;
      float sw, cw;
      __sincosf(ang, &sw, &cw);
      float br = re[c][i1], bi = im[c][i1];
      float tr = br * cw - bi * sw;
      float ti = br * sw + bi * cw;
      float ar = re[c][i0], ai = im[c][i0];
      re[c][i1] = ar - tr; im[c][i1] = ai - ti;
      re[c][i0] = ar + tr; im[c][i0] = ai + ti;
    }
    __syncthreads();
  }
}

// forward fft2 (block-axis 4-pt DFT + 1024-pt FFT), one wg per (B,d)
__global__ __launch_bounds__(256) void fft_fwd(const float* __restrict__ xin,
    float* __restrict__ Xre, float* __restrict__ Xim) {
  __shared__ float re[4][1024];
  __shared__ float im[4][1024];
  int Bi = blockIdx.x / 48, d = blockIdx.x % 48;
  int tid = threadIdx.x;
  for (int n = tid; n < 1024; n += 256) {
    const float* p = xin + (size_t)(Bi * 1024 + n) * 192 + d;
    float v0 = p[0], v1 = p[48], v2 = p[96], v3 = p[144];
    float s02 = v0 + v2, d02 = v0 - v2, s13 = v1 + v3, d13 = v1 - v3;
    re[0][n] = s02 + s13; im[0][n] = 0.f;
    re[1][n] = d02;       im[1][n] = -d13;
    re[2][n] = s02 - s13; im[2][n] = 0.f;
    re[3][n] = d02;       im[3][n] = d13;
  }
  __syncthreads();
  fft1024(re, im, tid, -1.0f);
  for (int idx = tid; idx < 4096; idx += 256) {
    int c = idx >> 10, k = idx & 1023;
    size_t o = ((size_t)(Bi * 1024 + k) * 4 + c) * 48 + d;
    Xre[o] = re[c][k] * (1.f / 64.f);
    Xim[o] = im[c][k] * (1.f / 64.f);
  }
}

// weight transpose: [p][b][d][k] -> [p][b][k][d]
__global__ __launch_bounds__(256) void wtrans(const float* __restrict__ src,
    float* __restrict__ dst) {
  int e = blockIdx.x * 256 + threadIdx.x;
  if (e >= 18432) return;
  int kk = e % 48;
  int dd = (e / 48) % 48;
  int pb = e / 2304;
  dst[pb * 2304 + kk * 48 + dd] = src[pb * 2304 + dd * 48 + kk];
}

// frequency-domain 2-layer complex block matmul + relu + softshrink (in-place)
__global__ __launch_bounds__(64) void einfft_mix(float* __restrict__ Xre,
    float* __restrict__ Xim, const float* __restrict__ t1, const float* __restrict__ t2,
    const float* __restrict__ cb1, const float* __restrict__ cb2) {
  __shared__ float r1s[64 * 49];
  __shared__ float i1s[64 * 49];
  int blk = blockIdx.x;
  int Bi = blk >> 6;
  int b  = (blk >> 4) & 3;
  int lane = threadIdx.x;
  int k = ((blk & 15) << 6) + lane;
  const float* w1r = t1 + b * 2304;
  const float* w1i = t1 + 9216 + b * 2304;
  const float* w2r = t2 + b * 2304;
  const float* w2i = t2 + 9216 + b * 2304;
  const float* b1r = cb1 + b * 48;
  const float* b1i = cb1 + 192 + b * 48;
  const float* b2r = cb2 + b * 48;
  const float* b2i = cb2 + 192 + b * 48;
  size_t base = ((size_t)(Bi * 1024 + k) * 4 + b) * 48;
  float Xr[48], Xi[48];
  const float4* pr = reinterpret_cast<const float4*>(Xre + base);
  const float4* pi = reinterpret_cast<const float4*>(Xim + base);
#pragma unroll
  for (int q = 0; q < 12; ++q) {
    float4 vr = pr[q], vi = pi[q];
    Xr[4 * q + 0] = vr.x; Xr[4 * q + 1] = vr.y; Xr[4 * q + 2] = vr.z; Xr[4 * q + 3] = vr.w;
    Xi[4 * q + 0] = vi.x; Xi[4 * q + 1] = vi.y; Xi[4 * q + 2] = vi.z; Xi[4 * q + 3] = vi.w;
  }
  for (int j = 0; j < 48; ++j) {
    float ar = b1r[j], ai = b1i[j];
    const float* wr = w1r + j * 48;
    const float* wi = w1i + j * 48;
#pragma unroll
    for (int dd = 0; dd < 48; ++dd) {
      ar += Xr[dd] * wr[dd] - Xi[dd] * wi[dd];
      ai += Xr[dd] * wi[dd] + Xi[dd] * wr[dd];
    }
    r1s[lane * 49 + j] = fmaxf(ar, 0.f);
    i1s[lane * 49 + j] = fmaxf(ai, 0.f);
  }
  for (int j = 0; j < 48; ++j) {
    float ar = b2r[j], ai = b2i[j];
    const float* wr = w2r + j * 48;
    const float* wi = w2i + j * 48;
#pragma unroll
    for (int dd = 0; dd < 48; ++dd) {
      float rv = r1s[lane * 49 + dd], iv = i1s[lane * 49 + dd];
      ar += rv * wr[dd] - iv * wi[dd];
      ai += rv * wi[dd] + iv * wr[dd];
    }
    float zr = (ar > 0.01f) ? ar - 0.01f : ((ar < -0.01f) ? ar + 0.01f : 0.f);
    float zi = (ai > 0.01f) ? ai - 0.01f : ((ai < -0.01f) ? ai + 0.01f : 0.f);
    Xre[base + j] = zr;
    Xim[base + j] = zi;
  }
}

// inverse fft2 + take real + residual add -> final output
__global__ __launch_bounds__(256) void fft_inv(const float* __restrict__ Zre,
    const float* __restrict__ Zim, const float* __restrict__ x1, float* __restrict__ out) {
  __shared__ float re[4][1024];
  __shared__ float im[4][1024];
  int Bi = blockIdx.x / 48, d = blockIdx.x % 48;
  int tid = threadIdx.x;
  for (int idx = tid; idx < 4096; idx += 256) {
    int c = idx >> 10, k = idx & 1023;
    size_t o = ((size_t)(Bi * 1024 + k) * 4 + c) * 48 + d;
    re[c][k] = Zre[o];
    im[c][k] = Zim[o];
  }
  __syncthreads();
  fft1024(re, im, tid, 1.0f);
  for (int n = tid; n < 1024; n += 256) {
    float r0 = re[0][n], r1 = re[1][n], r2 = re[2][n], r3 = re[3][n];
    float i1 = im[1][n], i3 = im[3][n];
    float y0 = r0 + r1 + r2 + r3;
    float y1 = r0 - i1 - r2 + i3;
    float y2 = r0 - r1 + r2 - r3;
    float y3 = r0 + i1 - r2 - i3;
    size_t base = (size_t)(Bi * 1024 + n) * 192 + d;
    out[base]       = x1[base]       + y0 * (1.f / 64.f);
    out[base + 48]  = x1[base + 48]  + y1 * (1.f / 64.f);
    out[base + 96]  = x1[base + 96]  + y2 * (1.f / 64.f);
    out[base + 144] = x1[base + 144] + y3 * (1.f / 64.f);
  }
}

extern "C" void kernel_launch(void* const* d_in, const int* in_sizes, int n_in,
                              void* d_out, int out_size, void* d_ws, size_t ws_size,
                              hipStream_t stream) {
  const float* x         = (const float*)d_in[0];
  const float* ln1_w     = (const float*)d_in[1];
  const float* ln1_b     = (const float*)d_in[2];
  const float* in_proj_w = (const float*)d_in[3];
  const float* conv_w    = (const float*)d_in[4];
  const float* conv_b    = (const float*)d_in[5];
  const float* x_proj_w  = (const float*)d_in[6];
  const float* dt_proj_w = (const float*)d_in[7];
  const float* dt_proj_b = (const float*)d_in[8];
  const float* A_log     = (const float*)d_in[9];
  const float* Dvec      = (const float*)d_in[10];
  const float* out_proj_w= (const float*)d_in[11];
  const float* ln2_w     = (const float*)d_in[12];
  const float* ln2_b     = (const float*)d_in[13];
  const float* cw1       = (const float*)d_in[14];
  const float* cw2       = (const float*)d_in[15];
  const float* cb1       = (const float*)d_in[16];
  const float* cb2       = (const float*)d_in[17];
  float* out = (float*)d_out;
  float* ws  = (float*)d_ws;

  // workspace layout (floats); xln reused as x1 after in_proj consumes it.
  // P/S/Hi (scan chunk summaries, 786432 floats each) alias x2/Xre/Xim,
  // which are dead until after the scan completes.
  float* xln = ws;                       // 786432
  float* xz  = xln + 786432;             // 3145728
  float* xc  = xz  + 3145728;            // 1572864
  float* dbc = xc  + 1572864;            // 573440
  float* dlt = dbc + 573440;             // 1572864
  float* yv  = dlt + 1572864;            // 1572864
  float* x2  = yv  + 1572864;            // 786432
  float* Xre = x2  + 786432;             // 786432
  float* Xim = Xre + 786432;             // 786432
  float* t1  = Xim + 786432;             // 18432
  float* t2  = t1  + 18432;              // 18432
  float* Pb = x2;    // scan pass-1 products   (dead before ln2 writes x2)
  float* Sb = Xre;   // scan pass-1 partials   (dead before fft_fwd)
  float* Hi = Xim;   // per-chunk h_init       (dead before fft_fwd)

  ln_kernel<<<4096, 64, 0, stream>>>(x, ln1_w, ln1_b, xln);
  gemm_tn<<<dim3(12, 64), 256, 0, stream>>>(xln, in_proj_w, nullptr, xz, 4096, 768, 192);
  conv_silu<<<6144, 256, 0, stream>>>(xz, conv_w, conv_b, xc);
  gemm_tn<<<dim3(3, 64), 256, 0, stream>>>(xc, x_proj_w, nullptr, dbc, 4096, 140, 384);
  delta_kernel<<<6144, 256, 0, stream>>>(dbc, dt_proj_w, dt_proj_b, dlt);
  scan_p1<<<3072, 256, 0, stream>>>(dlt, xc, dbc, A_log, Pb, Sb);
  scan_p2<<<384, 256, 0, stream>>>(Pb, Sb, Hi);
  scan_p3<<<3072, 256, 0, stream>>>(dlt, xc, dbc, A_log, Hi, yv);
  gate_kernel<<<6144, 256, 0, stream>>>(yv, xc, xz, Dvec, yv);
  float* x1 = xln;
  gemm_tn<<<dim3(3, 64), 256, 0, stream>>>(yv, out_proj_w, x, x1, 4096, 192, 384);
  ln_kernel<<<4096, 64, 0, stream>>>(x1, ln2_w, ln2_b, x2);
  fft_fwd<<<192, 256, 0, stream>>>(x2, Xre, Xim);
  wtrans<<<72, 256, 0, stream>>>(cw1, t1);
  wtrans<<<72, 256, 0, stream>>>(cw2, t2);
  einfft_mix<<<256, 64, 0, stream>>>(Xre, Xim, t1, t2, cb1, cb2);
  fft_inv<<<192, 256, 0, stream>>>(Xre, Xim, x1, out);
}

// Round 3
// 592.120 us; speedup vs baseline: 1.5196x; 1.1804x over previous
//
#include <hip/hip_runtime.h>
#include <math.h>

#define PI_F 3.14159265358979323846f

// ---------------- wave reduce ----------------
__device__ __forceinline__ float wave_reduce_sum(float v) {
  v += __shfl_xor(v, 32, 64);
  v += __shfl_xor(v, 16, 64);
  v += __shfl_xor(v, 8, 64);
  v += __shfl_xor(v, 4, 64);
  v += __shfl_xor(v, 2, 64);
  v += __shfl_xor(v, 1, 64);
  return v;
}

// ---------------- LayerNorm: one 64-lane wave per token (C=192) ----------------
__global__ __launch_bounds__(64) void ln_kernel(const float* __restrict__ x,
    const float* __restrict__ w, const float* __restrict__ b, float* __restrict__ o) {
  int row = blockIdx.x;
  int lane = threadIdx.x;
  const float* xr = x + row * 192;
  float v0 = xr[lane], v1 = xr[lane + 64], v2 = xr[lane + 128];
  float s  = wave_reduce_sum(v0 + v1 + v2);
  float s2 = wave_reduce_sum(v0 * v0 + v1 * v1 + v2 * v2);
  float mu  = s * (1.f / 192.f);
  float var = s2 * (1.f / 192.f) - mu * mu;
  float rs  = rsqrtf(var + 1e-5f);
  float* orow = o + row * 192;
  orow[lane]       = (v0 - mu) * rs * w[lane]       + b[lane];
  orow[lane + 64]  = (v1 - mu) * rs * w[lane + 64]  + b[lane + 64];
  orow[lane + 128] = (v2 - mu) * rs * w[lane + 128] + b[lane + 128];
}

// ---------------- tiled GEMM: C[m,n] = sum_k A[m,k]*W[n,k] (+res) ----------------
__global__ __launch_bounds__(256) void gemm_tn(const float* __restrict__ A,
    const float* __restrict__ W, const float* __restrict__ res, float* __restrict__ C,
    int M, int N, int K) {
  __shared__ float As[64][33];
  __shared__ float Ws[32][65];
  int tid = threadIdx.x;
  int m0 = blockIdx.y * 64, n0 = blockIdx.x * 64;
  int tr = tid >> 4, tc = tid & 15;
  float acc[4][4] = {{0.f}};
  for (int kk = 0; kk < K; kk += 32) {
    for (int i = tid; i < 64 * 32; i += 256) {
      int m = i >> 5, k = i & 31;
      As[m][k] = A[(m0 + m) * K + kk + k];
      float v = 0.f;
      if (n0 + m < N) v = W[(n0 + m) * K + kk + k];
      Ws[k][m] = v;
    }
    __syncthreads();
#pragma unroll
    for (int k = 0; k < 32; ++k) {
      float a[4], bb[4];
#pragma unroll
      for (int i = 0; i < 4; ++i) a[i] = As[tr * 4 + i][k];
#pragma unroll
      for (int j = 0; j < 4; ++j) bb[j] = Ws[k][tc * 4 + j];
#pragma unroll
      for (int i = 0; i < 4; ++i)
#pragma unroll
        for (int j = 0; j < 4; ++j)
          acc[i][j] = fmaf(a[i], bb[j], acc[i][j]);
    }
    __syncthreads();
  }
#pragma unroll
  for (int i = 0; i < 4; ++i) {
    int m = m0 + tr * 4 + i;
#pragma unroll
    for (int j = 0; j < 4; ++j) {
      int n = n0 + tc * 4 + j;
      if (n < N) {
        float v = acc[i][j];
        if (res) v += res[m * N + n];
        C[m * N + n] = v;
      }
    }
  }
}

// ---------------- causal depthwise conv1d(k=4) + SiLU ----------------
__global__ __launch_bounds__(256) void conv_silu(const float* __restrict__ xz,
    const float* __restrict__ cw, const float* __restrict__ cb, float* __restrict__ xc) {
  int e = blockIdx.x * 256 + threadIdx.x;
  if (e >= 4 * 1024 * 384) return;
  int d = e % 384;
  int t = (e / 384) % 1024;
  int b = e / (384 * 1024);
  const float* base = xz + (size_t)(b * 1024) * 768 + d;
  float acc = cb[d];
#pragma unroll
  for (int j = 0; j < 4; ++j) {
    int tt = t - 3 + j;
    if (tt >= 0) acc += base[(size_t)tt * 768] * cw[d * 4 + j];
  }
  float sg = 1.f / (1.f + __expf(-acc));
  xc[e] = acc * sg;
}

// ---------------- delta = softplus(dt @ dt_proj_w^T + bias) ----------------
__global__ __launch_bounds__(256) void delta_kernel(const float* __restrict__ dbc,
    const float* __restrict__ dtw, const float* __restrict__ dtb, float* __restrict__ dlt) {
  int e = blockIdx.x * 256 + threadIdx.x;
  if (e >= 4096 * 384) return;
  int d = e % 384;
  int t = e / 384;
  float s = dtb[d];
  const float* dtv = dbc + t * 140;
#pragma unroll
  for (int r = 0; r < 12; ++r) s += dtv[r] * dtw[d * 12 + r];
  dlt[e] = (s > 20.f) ? s : log1pf(__expf(s));
}

// ---------------- chunked selective scan (8 chunks x 128 steps) ----------------
__global__ __launch_bounds__(256) void scan_p1(const float* __restrict__ dlt,
    const float* __restrict__ xc, const float* __restrict__ dbc,
    const float* __restrict__ A_log, float* __restrict__ P, float* __restrict__ S) {
  int gw = (blockIdx.x * 256 + threadIdx.x) >> 6;  // [0, 12288)
  int lane = threadIdx.x & 63;
  int c  = gw & 7;
  int bd = gw >> 3;
  int b = bd / 384, d = bd % 384;
  float A = -__expf(A_log[d * 64 + lane]);
  int t0 = c * 128;
  const float* dp = dlt + ((size_t)b * 1024 + t0) * 384 + d;
  const float* xp = xc  + ((size_t)b * 1024 + t0) * 384 + d;
  const float* Bp = dbc + ((size_t)b * 1024 + t0) * 140 + 12 + lane;
  float Pv = 1.f, Sv = 0.f;
#pragma unroll 4
  for (int t = 0; t < 128; ++t) {
    float dv = dp[(size_t)t * 384];
    float xv = xp[(size_t)t * 384];
    float Bv = Bp[(size_t)t * 140];
    float a = __expf(dv * A);
    Pv *= a;
    Sv = fmaf(Sv, a, dv * xv * Bv);
  }
  size_t o = (size_t)gw * 64 + lane;   // layout [bd][c][n]
  P[o] = Pv;
  S[o] = Sv;
}

__global__ __launch_bounds__(256) void scan_p2(const float* __restrict__ P,
    const float* __restrict__ S, float* __restrict__ Hi) {
  int bd = (blockIdx.x * 256 + threadIdx.x) >> 6;  // [0, 1536)
  int lane = threadIdx.x & 63;
  size_t base = (size_t)bd * 8 * 64 + lane;
  float H = 0.f;
  Hi[base] = 0.f;
#pragma unroll
  for (int c = 1; c < 8; ++c) {
    float Pv = P[base + (size_t)(c - 1) * 64];
    float Sv = S[base + (size_t)(c - 1) * 64];
    H = fmaf(Pv, H, Sv);
    Hi[base + (size_t)c * 64] = H;
  }
}

__global__ __launch_bounds__(256) void scan_p3(const float* __restrict__ dlt,
    const float* __restrict__ xc, const float* __restrict__ dbc,
    const float* __restrict__ A_log, const float* __restrict__ Hi,
    float* __restrict__ y) {
  int gw = (blockIdx.x * 256 + threadIdx.x) >> 6;
  int lane = threadIdx.x & 63;
  int c  = gw & 7;
  int bd = gw >> 3;
  int b = bd / 384, d = bd % 384;
  float A = -__expf(A_log[d * 64 + lane]);
  int t0 = c * 128;
  const float* dp = dlt + ((size_t)b * 1024 + t0) * 384 + d;
  const float* xp = xc  + ((size_t)b * 1024 + t0) * 384 + d;
  const float* Bp = dbc + ((size_t)b * 1024 + t0) * 140 + 12 + lane;
  const float* Cp = dbc + ((size_t)b * 1024 + t0) * 140 + 76 + lane;
  float* yp = y + ((size_t)b * 1024 + t0) * 384 + d;
  float h = Hi[(size_t)gw * 64 + lane];
#pragma unroll 2
  for (int t = 0; t < 128; ++t) {
    float dv = dp[(size_t)t * 384];
    float xv = xp[(size_t)t * 384];
    float Bv = Bp[(size_t)t * 140];
    float Cv = Cp[(size_t)t * 140];
    float a = __expf(dv * A);
    h = fmaf(h, a, dv * xv * Bv);
    float p = wave_reduce_sum(h * Cv);
    if (lane == 0) yp[(size_t)t * 384] = p;
  }
}

// ---------------- gating: yg = (y + xc*D) * silu(z) ----------------
__global__ __launch_bounds__(256) void gate_kernel(float* __restrict__ y,
    const float* __restrict__ xc, const float* __restrict__ xz,
    const float* __restrict__ D, float* __restrict__ yg) {
  int e = blockIdx.x * 256 + threadIdx.x;
  if (e >= 4096 * 384) return;
  int d = e % 384;
  int row = e / 384;
  float zv = xz[(size_t)row * 768 + 384 + d];
  float sg = zv / (1.f + __expf(-zv));
  yg[e] = (y[e] + xc[e] * D[d]) * sg;
}

// ---------------- 1024-pt radix-2 FFT on 4 LDS columns ----------------
__device__ void fft1024(float (*re)[1024], float (*im)[1024], int tid, float sgn) {
  for (int idx = tid; idx < 4096; idx += 256) {
    int c = idx >> 10, i = idx & 1023;
    int r = (int)(__brev((unsigned)i) >> 22);
    if (i < r) {
      float tr = re[c][i]; re[c][i] = re[c][r]; re[c][r] = tr;
      float ti = im[c][i]; im[c][i] = im[c][r]; im[c][r] = ti;
    }
  }
  __syncthreads();
  for (int s = 0; s < 10; ++s) {
    int half = 1 << s;
    for (int u = tid; u < 2048; u += 256) {
      int c = u >> 9, v = u & 511;
      int j = v & (half - 1);
      int i0 = ((v >> s) << (s + 1)) + j;
      int i1 = i0 + half;
      float ang = sgn * PI_F * (float)j / (float)half;
      float sw, cw;
      __sincosf(ang, &sw, &cw);
      float br = re[c][i1], bi = im[c][i1];
      float tr = br * cw - bi * sw;
      float ti = br * sw + bi * cw;
      float ar = re[c][i0], ai = im[c][i0];
      re[c][i1] = ar - tr; im[c][i1] = ai - ti;
      re[c][i0] = ar + tr; im[c][i0] = ai + ti;
    }
    __syncthreads();
  }
}

// forward fft2 (block-axis 4-pt DFT + 1024-pt FFT), one wg per (B,d)
__global__ __launch_bounds__(256) void fft_fwd(const float* __restrict__ xin,
    float* __restrict__ Xre, float* __restrict__ Xim) {
  __shared__ float re[4][1024];
  __shared__ float im[4][1024];
  int Bi = blockIdx.x / 48, d = blockIdx.x % 48;
  int tid = threadIdx.x;
  for (int n = tid; n < 1024; n += 256) {
    const float* p = xin + (size_t)(Bi * 1024 + n) * 192 + d;
    float v0 = p[0], v1 = p[48], v2 = p[96], v3 = p[144];
    float s02 = v0 + v2, d02 = v0 - v2, s13 = v1 + v3, d13 = v1 - v3;
    re[0][n] = s02 + s13; im[0][n] = 0.f;
    re[1][n] = d02;       im[1][n] = -d13;
    re[2][n] = s02 - s13; im[2][n] = 0.f;
    re[3][n] = d02;       im[3][n] = d13;
  }
  __syncthreads();
  fft1024(re, im, tid, -1.0f);
  for (int idx = tid; idx < 4096; idx += 256) {
    int c = idx >> 10, k = idx & 1023;
    size_t o = ((size_t)(Bi * 1024 + k) * 4 + c) * 48 + d;
    Xre[o] = re[c][k] * (1.f / 64.f);
    Xim[o] = im[c][k] * (1.f / 64.f);
  }
}

// ---------------- EinFFT frequency mix, layer 1: one thread per (row, j) ----
// row = (Bi*1024 + k)*4 + b over 16384 rows; X stored [row][48].
// r1/i1[row][j] = relu( sum_dd Xr*w1r -/+ Xi*w1i + cb1 ), weights in
// ORIGINAL [b][d][k] layout -> lane-coalesced at address dd*48+j.
__global__ __launch_bounds__(256) void mix_l1(const float* __restrict__ Xre,
    const float* __restrict__ Xim, const float* __restrict__ cw1,
    const float* __restrict__ cb1, float* __restrict__ r1, float* __restrict__ i1) {
  int e = blockIdx.x * 256 + threadIdx.x;   // [0, 786432)
  int j = e % 48;
  int row = e / 48;
  int b = row & 3;
  const float* wr = cw1 + b * 2304;
  const float* wi = cw1 + 9216 + b * 2304;
  const float* xr = Xre + (size_t)row * 48;
  const float* xi = Xim + (size_t)row * 48;
  float ar = cb1[b * 48 + j];
  float ai = cb1[192 + b * 48 + j];
#pragma unroll 12
  for (int dd = 0; dd < 48; ++dd) {
    float xrv = xr[dd], xiv = xi[dd];
    float wrv = wr[dd * 48 + j], wiv = wi[dd * 48 + j];
    ar = fmaf(xrv, wrv, ar);
    ar = fmaf(-xiv, wiv, ar);
    ai = fmaf(xrv, wiv, ai);
    ai = fmaf(xiv, wrv, ai);
  }
  r1[e] = fmaxf(ar, 0.f);
  i1[e] = fmaxf(ai, 0.f);
}

// layer 2 + softshrink, writes Z in-place over X
__global__ __launch_bounds__(256) void mix_l2(const float* __restrict__ r1,
    const float* __restrict__ i1, const float* __restrict__ cw2,
    const float* __restrict__ cb2, float* __restrict__ Xre, float* __restrict__ Xim) {
  int e = blockIdx.x * 256 + threadIdx.x;
  int j = e % 48;
  int row = e / 48;
  int b = row & 3;
  const float* wr = cw2 + b * 2304;
  const float* wi = cw2 + 9216 + b * 2304;
  const float* rr = r1 + (size_t)row * 48;
  const float* ri = i1 + (size_t)row * 48;
  float ar = cb2[b * 48 + j];
  float ai = cb2[192 + b * 48 + j];
#pragma unroll 12
  for (int dd = 0; dd < 48; ++dd) {
    float rv = rr[dd], iv = ri[dd];
    float wrv = wr[dd * 48 + j], wiv = wi[dd * 48 + j];
    ar = fmaf(rv, wrv, ar);
    ar = fmaf(-iv, wiv, ar);
    ai = fmaf(rv, wiv, ai);
    ai = fmaf(iv, wrv, ai);
  }
  float zr = (ar > 0.01f) ? ar - 0.01f : ((ar < -0.01f) ? ar + 0.01f : 0.f);
  float zi = (ai > 0.01f) ? ai - 0.01f : ((ai < -0.01f) ? ai + 0.01f : 0.f);
  Xre[e] = zr;
  Xim[e] = zi;
}

// inverse fft2 + take real + residual add -> final output
__global__ __launch_bounds__(256) void fft_inv(const float* __restrict__ Zre,
    const float* __restrict__ Zim, const float* __restrict__ x1, float* __restrict__ out) {
  __shared__ float re[4][1024];
  __shared__ float im[4][1024];
  int Bi = blockIdx.x / 48, d = blockIdx.x % 48;
  int tid = threadIdx.x;
  for (int idx = tid; idx < 4096; idx += 256) {
    int c = idx >> 10, k = idx & 1023;
    size_t o = ((size_t)(Bi * 1024 + k) * 4 + c) * 48 + d;
    re[c][k] = Zre[o];
    im[c][k] = Zim[o];
  }
  __syncthreads();
  fft1024(re, im, tid, 1.0f);
  for (int n = tid; n < 1024; n += 256) {
    float r0 = re[0][n], r1 = re[1][n], r2 = re[2][n], r3 = re[3][n];
    float i1 = im[1][n], i3 = im[3][n];
    float y0 = r0 + r1 + r2 + r3;
    float y1 = r0 - i1 - r2 + i3;
    float y2 = r0 - r1 + r2 - r3;
    float y3 = r0 + i1 - r2 - i3;
    size_t base = (size_t)(Bi * 1024 + n) * 192 + d;
    out[base]       = x1[base]       + y0 * (1.f / 64.f);
    out[base + 48]  = x1[base + 48]  + y1 * (1.f / 64.f);
    out[base + 96]  = x1[base + 96]  + y2 * (1.f / 64.f);
    out[base + 144] = x1[base + 144] + y3 * (1.f / 64.f);
  }
}

extern "C" void kernel_launch(void* const* d_in, const int* in_sizes, int n_in,
                              void* d_out, int out_size, void* d_ws, size_t ws_size,
                              hipStream_t stream) {
  const float* x         = (const float*)d_in[0];
  const float* ln1_w     = (const float*)d_in[1];
  const float* ln1_b     = (const float*)d_in[2];
  const float* in_proj_w = (const float*)d_in[3];
  const float* conv_w    = (const float*)d_in[4];
  const float* conv_b    = (const float*)d_in[5];
  const float* x_proj_w  = (const float*)d_in[6];
  const float* dt_proj_w = (const float*)d_in[7];
  const float* dt_proj_b = (const float*)d_in[8];
  const float* A_log     = (const float*)d_in[9];
  const float* Dvec      = (const float*)d_in[10];
  const float* out_proj_w= (const float*)d_in[11];
  const float* ln2_w     = (const float*)d_in[12];
  const float* ln2_b     = (const float*)d_in[13];
  const float* cw1       = (const float*)d_in[14];
  const float* cw2       = (const float*)d_in[15];
  const float* cb1       = (const float*)d_in[16];
  const float* cb2       = (const float*)d_in[17];
  float* out = (float*)d_out;
  float* ws  = (float*)d_ws;

  // workspace layout (floats); aliases:
  //  P/S/Hi (scan summaries) alias x2/Xre/Xim (dead until after scan)
  //  r1/i1 (einfft layer-1 out) alias dlt/yv (dead after scan/out_proj)
  float* xln = ws;                       // 786432
  float* xz  = xln + 786432;             // 3145728
  float* xc  = xz  + 3145728;            // 1572864
  float* dbc = xc  + 1572864;            // 573440
  float* dlt = dbc + 573440;             // 1572864
  float* yv  = dlt + 1572864;            // 1572864
  float* x2  = yv  + 1572864;            // 786432
  float* Xre = x2  + 786432;             // 786432
  float* Xim = Xre + 786432;             // 786432
  float* Pb = x2;    // scan pass-1 products
  float* Sb = Xre;   // scan pass-1 partials
  float* Hi = Xim;   // per-chunk h_init
  float* r1 = dlt;   // einfft layer-1 real
  float* i1 = yv;    // einfft layer-1 imag

  ln_kernel<<<4096, 64, 0, stream>>>(x, ln1_w, ln1_b, xln);
  gemm_tn<<<dim3(12, 64), 256, 0, stream>>>(xln, in_proj_w, nullptr, xz, 4096, 768, 192);
  conv_silu<<<6144, 256, 0, stream>>>(xz, conv_w, conv_b, xc);
  gemm_tn<<<dim3(3, 64), 256, 0, stream>>>(xc, x_proj_w, nullptr, dbc, 4096, 140, 384);
  delta_kernel<<<6144, 256, 0, stream>>>(dbc, dt_proj_w, dt_proj_b, dlt);
  scan_p1<<<3072, 256, 0, stream>>>(dlt, xc, dbc, A_log, Pb, Sb);
  scan_p2<<<384, 256, 0, stream>>>(Pb, Sb, Hi);
  scan_p3<<<3072, 256, 0, stream>>>(dlt, xc, dbc, A_log, Hi, yv);
  gate_kernel<<<6144, 256, 0, stream>>>(yv, xc, xz, Dvec, yv);
  float* x1 = xln;
  gemm_tn<<<dim3(3, 64), 256, 0, stream>>>(yv, out_proj_w, x, x1, 4096, 192, 384);
  ln_kernel<<<4096, 64, 0, stream>>>(x1, ln2_w, ln2_b, x2);
  fft_fwd<<<192, 256, 0, stream>>>(x2, Xre, Xim);
  mix_l1<<<3072, 256, 0, stream>>>(Xre, Xim, cw1, cb1, r1, i1);
  mix_l2<<<3072, 256, 0, stream>>>(r1, i1, cw2, cb2, Xre, Xim);
  fft_inv<<<192, 256, 0, stream>>>(Xre, Xim, x1, out);
}

// Round 4
// 506.383 us; speedup vs baseline: 1.7769x; 1.1693x over previous
//
#include <hip/hip_runtime.h>
#include <math.h>

#define PI_F 3.14159265358979323846f

// ---------------- wave reduce ----------------
__device__ __forceinline__ float wave_reduce_sum(float v) {
  v += __shfl_xor(v, 32, 64);
  v += __shfl_xor(v, 16, 64);
  v += __shfl_xor(v, 8, 64);
  v += __shfl_xor(v, 4, 64);
  v += __shfl_xor(v, 2, 64);
  v += __shfl_xor(v, 1, 64);
  return v;
}

// ---------------- LayerNorm: one 64-lane wave per token (C=192) ----------------
__global__ __launch_bounds__(64) void ln_kernel(const float* __restrict__ x,
    const float* __restrict__ w, const float* __restrict__ b, float* __restrict__ o) {
  int row = blockIdx.x;
  int lane = threadIdx.x;
  const float* xr = x + row * 192;
  float v0 = xr[lane], v1 = xr[lane + 64], v2 = xr[lane + 128];
  float s  = wave_reduce_sum(v0 + v1 + v2);
  float s2 = wave_reduce_sum(v0 * v0 + v1 * v1 + v2 * v2);
  float mu  = s * (1.f / 192.f);
  float var = s2 * (1.f / 192.f) - mu * mu;
  float rs  = rsqrtf(var + 1e-5f);
  float* orow = o + row * 192;
  orow[lane]       = (v0 - mu) * rs * w[lane]       + b[lane];
  orow[lane + 64]  = (v1 - mu) * rs * w[lane + 64]  + b[lane + 64];
  orow[lane + 128] = (v2 - mu) * rs * w[lane + 128] + b[lane + 128];
}

// ---------------- tiled GEMM: C[m,n] = sum_k A[m,k]*W[n,k] (+res) ----------------
__global__ __launch_bounds__(256) void gemm_tn(const float* __restrict__ A,
    const float* __restrict__ W, const float* __restrict__ res, float* __restrict__ C,
    int M, int N, int K) {
  __shared__ float As[64][33];
  __shared__ float Ws[32][65];
  int tid = threadIdx.x;
  int m0 = blockIdx.y * 64, n0 = blockIdx.x * 64;
  int tr = tid >> 4, tc = tid & 15;
  float acc[4][4] = {{0.f}};
  for (int kk = 0; kk < K; kk += 32) {
    for (int i = tid; i < 64 * 32; i += 256) {
      int m = i >> 5, k = i & 31;
      As[m][k] = A[(m0 + m) * K + kk + k];
      float v = 0.f;
      if (n0 + m < N) v = W[(n0 + m) * K + kk + k];
      Ws[k][m] = v;
    }
    __syncthreads();
#pragma unroll
    for (int k = 0; k < 32; ++k) {
      float a[4], bb[4];
#pragma unroll
      for (int i = 0; i < 4; ++i) a[i] = As[tr * 4 + i][k];
#pragma unroll
      for (int j = 0; j < 4; ++j) bb[j] = Ws[k][tc * 4 + j];
#pragma unroll
      for (int i = 0; i < 4; ++i)
#pragma unroll
        for (int j = 0; j < 4; ++j)
          acc[i][j] = fmaf(a[i], bb[j], acc[i][j]);
    }
    __syncthreads();
  }
#pragma unroll
  for (int i = 0; i < 4; ++i) {
    int m = m0 + tr * 4 + i;
#pragma unroll
    for (int j = 0; j < 4; ++j) {
      int n = n0 + tc * 4 + j;
      if (n < N) {
        float v = acc[i][j];
        if (res) v += res[m * N + n];
        C[m * N + n] = v;
      }
    }
  }
}

// ---------------- causal depthwise conv1d(k=4) + SiLU ----------------
__global__ __launch_bounds__(256) void conv_silu(const float* __restrict__ xz,
    const float* __restrict__ cw, const float* __restrict__ cb, float* __restrict__ xc) {
  int e = blockIdx.x * 256 + threadIdx.x;
  if (e >= 4 * 1024 * 384) return;
  int d = e % 384;
  int t = (e / 384) % 1024;
  int b = e / (384 * 1024);
  const float* base = xz + (size_t)(b * 1024) * 768 + d;
  float acc = cb[d];
#pragma unroll
  for (int j = 0; j < 4; ++j) {
    int tt = t - 3 + j;
    if (tt >= 0) acc += base[(size_t)tt * 768] * cw[d * 4 + j];
  }
  float sg = 1.f / (1.f + __expf(-acc));
  xc[e] = acc * sg;
}

// ---------------- delta = softplus(dt @ dt_proj_w^T + bias) ----------------
__global__ __launch_bounds__(256) void delta_kernel(const float* __restrict__ dbc,
    const float* __restrict__ dtw, const float* __restrict__ dtb, float* __restrict__ dlt) {
  int e = blockIdx.x * 256 + threadIdx.x;
  if (e >= 4096 * 384) return;
  int d = e % 384;
  int t = e / 384;
  float s = dtb[d];
  const float* dtv = dbc + t * 140;
#pragma unroll
  for (int r = 0; r < 12; ++r) s += dtv[r] * dtw[d * 12 + r];
  dlt[e] = (s > 20.f) ? s : log1pf(__expf(s));
}

// ---------------- chunked selective scan (8 chunks x 128 steps) ----------------
__global__ __launch_bounds__(256) void scan_p1(const float* __restrict__ dlt,
    const float* __restrict__ xc, const float* __restrict__ dbc,
    const float* __restrict__ A_log, float* __restrict__ P, float* __restrict__ S) {
  int gw = (blockIdx.x * 256 + threadIdx.x) >> 6;  // [0, 12288)
  int lane = threadIdx.x & 63;
  int c  = gw & 7;
  int bd = gw >> 3;
  int b = bd / 384, d = bd % 384;
  float A = -__expf(A_log[d * 64 + lane]);
  int t0 = c * 128;
  const float* dp = dlt + ((size_t)b * 1024 + t0) * 384 + d;
  const float* xp = xc  + ((size_t)b * 1024 + t0) * 384 + d;
  const float* Bp = dbc + ((size_t)b * 1024 + t0) * 140 + 12 + lane;
  float Pv = 1.f, Sv = 0.f;
#pragma unroll 4
  for (int t = 0; t < 128; ++t) {
    float dv = dp[(size_t)t * 384];
    float xv = xp[(size_t)t * 384];
    float Bv = Bp[(size_t)t * 140];
    float a = __expf(dv * A);
    Pv *= a;
    Sv = fmaf(Sv, a, dv * xv * Bv);
  }
  size_t o = (size_t)gw * 64 + lane;   // layout [bd][c][n]
  P[o] = Pv;
  S[o] = Sv;
}

__global__ __launch_bounds__(256) void scan_p2(const float* __restrict__ P,
    const float* __restrict__ S, float* __restrict__ Hi) {
  int bd = (blockIdx.x * 256 + threadIdx.x) >> 6;  // [0, 1536)
  int lane = threadIdx.x & 63;
  size_t base = (size_t)bd * 8 * 64 + lane;
  float H = 0.f;
  Hi[base] = 0.f;
#pragma unroll
  for (int c = 1; c < 8; ++c) {
    float Pv = P[base + (size_t)(c - 1) * 64];
    float Sv = S[base + (size_t)(c - 1) * 64];
    H = fmaf(Pv, H, Sv);
    Hi[base + (size_t)c * 64] = H;
  }
}

// pass 3 with transpose-reduce: buffer 16 timesteps of h*C in LDS, then
// each lane sums a 16-element row-chunk (ds_read_b128) + 2 shuffles.
// Replaces the 6-deep dependent shuffle chain per timestep (DS-latency bound).
__global__ __launch_bounds__(256) void scan_p3(const float* __restrict__ dlt,
    const float* __restrict__ xc, const float* __restrict__ dbc,
    const float* __restrict__ A_log, const float* __restrict__ Hi,
    float* __restrict__ y) {
  __shared__ float tile[4][16][68];   // [wave][t][n], pad 68 keeps b128 aligned
  int w = threadIdx.x >> 6;
  int gw = (blockIdx.x * 256 + threadIdx.x) >> 6;
  int lane = threadIdx.x & 63;
  int c  = gw & 7;
  int bd = gw >> 3;
  int b = bd / 384, d = bd % 384;
  float A = -__expf(A_log[d * 64 + lane]);
  int t0 = c * 128;
  const float* dp = dlt + ((size_t)b * 1024 + t0) * 384 + d;
  const float* xp = xc  + ((size_t)b * 1024 + t0) * 384 + d;
  const float* Bp = dbc + ((size_t)b * 1024 + t0) * 140 + 12 + lane;
  const float* Cp = dbc + ((size_t)b * 1024 + t0) * 140 + 76 + lane;
  float* yp = y + ((size_t)b * 1024 + t0) * 384 + d;
  float h = Hi[(size_t)gw * 64 + lane];
  int tq = lane & 15;
  int q  = lane >> 4;
  for (int tb = 0; tb < 128; tb += 16) {
#pragma unroll
    for (int tt = 0; tt < 16; ++tt) {
      int t = tb + tt;
      float dv = dp[(size_t)t * 384];
      float xv = xp[(size_t)t * 384];
      float Bv = Bp[(size_t)t * 140];
      float Cv = Cp[(size_t)t * 140];
      float a = __expf(dv * A);
      h = fmaf(h, a, dv * xv * Bv);
      tile[w][tt][lane] = h * Cv;
    }
    const float* trow = &tile[w][tq][q * 16];
    float s = 0.f;
#pragma unroll
    for (int i = 0; i < 16; ++i) s += trow[i];
    s += __shfl_xor(s, 16, 64);
    s += __shfl_xor(s, 32, 64);
    if (lane < 16) yp[(size_t)(tb + lane) * 384] = s;
  }
}

// ---------------- gating: yg = (y + xc*D) * silu(z) ----------------
__global__ __launch_bounds__(256) void gate_kernel(float* __restrict__ y,
    const float* __restrict__ xc, const float* __restrict__ xz,
    const float* __restrict__ D, float* __restrict__ yg) {
  int e = blockIdx.x * 256 + threadIdx.x;
  if (e >= 4096 * 384) return;
  int d = e % 384;
  int row = e / 384;
  float zv = xz[(size_t)row * 768 + 384 + d];
  float sg = zv / (1.f + __expf(-zv));
  yg[e] = (y[e] + xc[e] * D[d]) * sg;
}

// ---------------- single-column 1024-pt radix-2 FFT in LDS ----------------
__device__ __forceinline__ void fft1024c(float* __restrict__ re,
    float* __restrict__ im, int tid, float sgn) {
  for (int i = tid; i < 1024; i += 256) {
    int r = (int)(__brev((unsigned)i) >> 22);
    if (i < r) {
      float tr = re[i]; re[i] = re[r]; re[r] = tr;
      float ti = im[i]; im[i] = im[r]; im[r] = ti;
    }
  }
  __syncthreads();
  for (int s = 0; s < 10; ++s) {
    int half = 1 << s;
#pragma unroll
    for (int uu = 0; uu < 2; ++uu) {
      int u = tid + uu * 256;
      int j = u & (half - 1);
      int i0 = ((u >> s) << (s + 1)) + j;
      int i1 = i0 + half;
      float ang = sgn * PI_F * (float)j / (float)half;
      float sw, cw;
      __sincosf(ang, &sw, &cw);
      float br = re[i1], bi = im[i1];
      float tr = br * cw - bi * sw;
      float ti = br * sw + bi * cw;
      float ar = re[i0], ai = im[i0];
      re[i1] = ar - tr; im[i1] = ai - ti;
      re[i0] = ar + tr; im[i0] = ai + ti;
    }
    __syncthreads();
  }
}

// forward fft2: one block per (Bi,d,c). Inline 4-pt DFT over c on load
// (DFT4 commutes with the n-axis FFT), then one 1024-pt FFT.
__global__ __launch_bounds__(256) void fft_fwd(const float* __restrict__ xin,
    float* __restrict__ Xre, float* __restrict__ Xim) {
  __shared__ float re[1024];
  __shared__ float im[1024];
  int blk = blockIdx.x;
  int c = blk & 3;
  int rest = blk >> 2;
  int d = rest % 48, Bi = rest / 48;
  int tid = threadIdx.x;
  for (int n = tid; n < 1024; n += 256) {
    const float* p = xin + (size_t)(Bi * 1024 + n) * 192 + d;
    float v0 = p[0], v1 = p[48], v2 = p[96], v3 = p[144];
    float rr, ii;
    if (c == 0)      { rr = v0 + v1 + v2 + v3; ii = 0.f; }
    else if (c == 1) { rr = v0 - v2;           ii = -(v1 - v3); }
    else if (c == 2) { rr = v0 - v1 + v2 - v3; ii = 0.f; }
    else             { rr = v0 - v2;           ii = (v1 - v3); }
    re[n] = rr; im[n] = ii;
  }
  __syncthreads();
  fft1024c(re, im, tid, -1.0f);
  for (int k = tid; k < 1024; k += 256) {
    size_t o = ((size_t)(Bi * 1024 + k) * 4 + c) * 48 + d;
    Xre[o] = re[k] * (1.f / 64.f);
    Xim[o] = im[k] * (1.f / 64.f);
  }
}

// ---------------- EinFFT frequency mix, layer 1: one thread per (row, j) ----
__global__ __launch_bounds__(256) void mix_l1(const float* __restrict__ Xre,
    const float* __restrict__ Xim, const float* __restrict__ cw1,
    const float* __restrict__ cb1, float* __restrict__ r1, float* __restrict__ i1) {
  int e = blockIdx.x * 256 + threadIdx.x;   // [0, 786432)
  int j = e % 48;
  int row = e / 48;
  int b = row & 3;
  const float* wr = cw1 + b * 2304;
  const float* wi = cw1 + 9216 + b * 2304;
  const float* xr = Xre + (size_t)row * 48;
  const float* xi = Xim + (size_t)row * 48;
  float ar = cb1[b * 48 + j];
  float ai = cb1[192 + b * 48 + j];
#pragma unroll 12
  for (int dd = 0; dd < 48; ++dd) {
    float xrv = xr[dd], xiv = xi[dd];
    float wrv = wr[dd * 48 + j], wiv = wi[dd * 48 + j];
    ar = fmaf(xrv, wrv, ar);
    ar = fmaf(-xiv, wiv, ar);
    ai = fmaf(xrv, wiv, ai);
    ai = fmaf(xiv, wrv, ai);
  }
  r1[e] = fmaxf(ar, 0.f);
  i1[e] = fmaxf(ai, 0.f);
}

// layer 2 + softshrink, writes Z in-place over X
__global__ __launch_bounds__(256) void mix_l2(const float* __restrict__ r1,
    const float* __restrict__ i1, const float* __restrict__ cw2,
    const float* __restrict__ cb2, float* __restrict__ Xre, float* __restrict__ Xim) {
  int e = blockIdx.x * 256 + threadIdx.x;
  int j = e % 48;
  int row = e / 48;
  int b = row & 3;
  const float* wr = cw2 + b * 2304;
  const float* wi = cw2 + 9216 + b * 2304;
  const float* rr = r1 + (size_t)row * 48;
  const float* ri = i1 + (size_t)row * 48;
  float ar = cb2[b * 48 + j];
  float ai = cb2[192 + b * 48 + j];
#pragma unroll 12
  for (int dd = 0; dd < 48; ++dd) {
    float rv = rr[dd], iv = ri[dd];
    float wrv = wr[dd * 48 + j], wiv = wi[dd * 48 + j];
    ar = fmaf(rv, wrv, ar);
    ar = fmaf(-iv, wiv, ar);
    ai = fmaf(rv, wiv, ai);
    ai = fmaf(iv, wrv, ai);
  }
  float zr = (ar > 0.01f) ? ar - 0.01f : ((ar < -0.01f) ? ar + 0.01f : 0.f);
  float zi = (ai > 0.01f) ? ai - 0.01f : ((ai < -0.01f) ? ai + 0.01f : 0.f);
  Xre[e] = zr;
  Xim[e] = zi;
}

// inverse fft2: one block per (Bi,d,c). Inline inverse 4-pt DFT over c on
// load (commutes with the k-axis IFFT), IFFT, add residual, write real part.
__global__ __launch_bounds__(256) void fft_inv(const float* __restrict__ Zre,
    const float* __restrict__ Zim, const float* __restrict__ x1, float* __restrict__ out) {
  __shared__ float re[1024];
  __shared__ float im[1024];
  int blk = blockIdx.x;
  int c = blk & 3;
  int rest = blk >> 2;
  int d = rest % 48, Bi = rest / 48;
  int tid = threadIdx.x;
  for (int k = tid; k < 1024; k += 256) {
    size_t o = ((size_t)(Bi * 1024 + k) * 4) * 48 + d;
    float r0 = Zre[o], r1v = Zre[o + 48], r2 = Zre[o + 96], r3 = Zre[o + 144];
    float i0 = Zim[o], i1v = Zim[o + 48], i2 = Zim[o + 96], i3 = Zim[o + 144];
    float rr, ii;
    if (c == 0)      { rr = r0 + r1v + r2 + r3;  ii = i0 + i1v + i2 + i3; }
    else if (c == 1) { rr = r0 - i1v - r2 + i3;  ii = i0 + r1v - i2 - r3; }
    else if (c == 2) { rr = r0 - r1v + r2 - r3;  ii = i0 - i1v + i2 - i3; }
    else             { rr = r0 + i1v - r2 - i3;  ii = i0 - r1v - i2 + r3; }
    re[k] = rr; im[k] = ii;
  }
  __syncthreads();
  fft1024c(re, im, tid, 1.0f);
  for (int n = tid; n < 1024; n += 256) {
    size_t o = (size_t)(Bi * 1024 + n) * 192 + c * 48 + d;
    out[o] = x1[o] + re[n] * (1.f / 64.f);
  }
}

extern "C" void kernel_launch(void* const* d_in, const int* in_sizes, int n_in,
                              void* d_out, int out_size, void* d_ws, size_t ws_size,
                              hipStream_t stream) {
  const float* x         = (const float*)d_in[0];
  const float* ln1_w     = (const float*)d_in[1];
  const float* ln1_b     = (const float*)d_in[2];
  const float* in_proj_w = (const float*)d_in[3];
  const float* conv_w    = (const float*)d_in[4];
  const float* conv_b    = (const float*)d_in[5];
  const float* x_proj_w  = (const float*)d_in[6];
  const float* dt_proj_w = (const float*)d_in[7];
  const float* dt_proj_b = (const float*)d_in[8];
  const float* A_log     = (const float*)d_in[9];
  const float* Dvec      = (const float*)d_in[10];
  const float* out_proj_w= (const float*)d_in[11];
  const float* ln2_w     = (const float*)d_in[12];
  const float* ln2_b     = (const float*)d_in[13];
  const float* cw1       = (const float*)d_in[14];
  const float* cw2       = (const float*)d_in[15];
  const float* cb1       = (const float*)d_in[16];
  const float* cb2       = (const float*)d_in[17];
  float* out = (float*)d_out;
  float* ws  = (float*)d_ws;

  // workspace layout (floats); aliases:
  //  P/S/Hi (scan summaries) alias x2/Xre/Xim (dead until after scan)
  //  r1/i1 (einfft layer-1 out) alias dlt/yv (dead after scan/out_proj)
  float* xln = ws;                       // 786432
  float* xz  = xln + 786432;             // 3145728
  float* xc  = xz  + 3145728;            // 1572864
  float* dbc = xc  + 1572864;            // 573440
  float* dlt = dbc + 573440;             // 1572864
  float* yv  = dlt + 1572864;            // 1572864
  float* x2  = yv  + 1572864;            // 786432
  float* Xre = x2  + 786432;             // 786432
  float* Xim = Xre + 786432;             // 786432
  float* Pb = x2;    // scan pass-1 products
  float* Sb = Xre;   // scan pass-1 partials
  float* Hi = Xim;   // per-chunk h_init
  float* r1 = dlt;   // einfft layer-1 real
  float* i1 = yv;    // einfft layer-1 imag

  ln_kernel<<<4096, 64, 0, stream>>>(x, ln1_w, ln1_b, xln);
  gemm_tn<<<dim3(12, 64), 256, 0, stream>>>(xln, in_proj_w, nullptr, xz, 4096, 768, 192);
  conv_silu<<<6144, 256, 0, stream>>>(xz, conv_w, conv_b, xc);
  gemm_tn<<<dim3(3, 64), 256, 0, stream>>>(xc, x_proj_w, nullptr, dbc, 4096, 140, 384);
  delta_kernel<<<6144, 256, 0, stream>>>(dbc, dt_proj_w, dt_proj_b, dlt);
  scan_p1<<<3072, 256, 0, stream>>>(dlt, xc, dbc, A_log, Pb, Sb);
  scan_p2<<<384, 256, 0, stream>>>(Pb, Sb, Hi);
  scan_p3<<<3072, 256, 0, stream>>>(dlt, xc, dbc, A_log, Hi, yv);
  gate_kernel<<<6144, 256, 0, stream>>>(yv, xc, xz, Dvec, yv);
  float* x1 = xln;
  gemm_tn<<<dim3(3, 64), 256, 0, stream>>>(yv, out_proj_w, x, x1, 4096, 192, 384);
  ln_kernel<<<4096, 64, 0, stream>>>(x1, ln2_w, ln2_b, x2);
  fft_fwd<<<768, 256, 0, stream>>>(x2, Xre, Xim);
  mix_l1<<<3072, 256, 0, stream>>>(Xre, Xim, cw1, cb1, r1, i1);
  mix_l2<<<3072, 256, 0, stream>>>(r1, i1, cw2, cb2, Xre, Xim);
  fft_inv<<<768, 256, 0, stream>>>(Xre, Xim, x1, out);
}

// Round 5
// 411.524 us; speedup vs baseline: 2.1865x; 1.2305x over previous
//
#include <hip/hip_runtime.h>
#include <math.h>

#define PI_F 3.14159265358979323846f

// ---------------- wave reduce ----------------
__device__ __forceinline__ float wave_reduce_sum(float v) {
  v += __shfl_xor(v, 32, 64);
  v += __shfl_xor(v, 16, 64);
  v += __shfl_xor(v, 8, 64);
  v += __shfl_xor(v, 4, 64);
  v += __shfl_xor(v, 2, 64);
  v += __shfl_xor(v, 1, 64);
  return v;
}

// ---------------- LayerNorm: one 64-lane wave per token (C=192) ----------------
__global__ __launch_bounds__(64) void ln_kernel(const float* __restrict__ x,
    const float* __restrict__ w, const float* __restrict__ b, float* __restrict__ o) {
  int row = blockIdx.x;
  int lane = threadIdx.x;
  const float* xr = x + row * 192;
  float v0 = xr[lane], v1 = xr[lane + 64], v2 = xr[lane + 128];
  float s  = wave_reduce_sum(v0 + v1 + v2);
  float s2 = wave_reduce_sum(v0 * v0 + v1 * v1 + v2 * v2);
  float mu  = s * (1.f / 192.f);
  float var = s2 * (1.f / 192.f) - mu * mu;
  float rs  = rsqrtf(var + 1e-5f);
  float* orow = o + row * 192;
  orow[lane]       = (v0 - mu) * rs * w[lane]       + b[lane];
  orow[lane + 64]  = (v1 - mu) * rs * w[lane + 64]  + b[lane + 64];
  orow[lane + 128] = (v2 - mu) * rs * w[lane + 128] + b[lane + 128];
}

// ---------------- pipelined tiled GEMM: C[m,n] = sum_k A[m,k]*W[n,k] (+res) ----
// BM=BN=64, BK=32, 256 thr, 4x4 micro. Register double-buffer prefetch:
// global loads for tile k+1 issue BEFORE compute on tile k (latency hidden
// under 1024 VALU cyc), LDS write + single barrier after. Tiles stored [k][m]
// (pad 68) so compute does 2x ds_read_b128 per k (broadcast/2-way = free).
__global__ __launch_bounds__(256) void gemm_tn(const float* __restrict__ A,
    const float* __restrict__ W, const float* __restrict__ res, float* __restrict__ C,
    int M, int N, int K) {
  __shared__ float As[2][32][68];   // [buf][k][m]
  __shared__ float Ws[2][32][68];   // [buf][k][n]
  int tid = threadIdx.x;
  int m0 = blockIdx.y * 64, n0 = blockIdx.x * 64;
  int tr = tid >> 4, tc = tid & 15;
  int sm  = tid >> 3;   // staging row (0..31), +32 for j=1
  int skq = tid & 7;    // staging float4 column (0..7)
  float4 aP[2], wP[2];
  // prologue: load tile 0
#pragma unroll
  for (int j = 0; j < 2; ++j) {
    int m = sm + j * 32;
    aP[j] = *(const float4*)(A + (size_t)(m0 + m) * K + skq * 4);
    int n = n0 + m;
    if (n < N) wP[j] = *(const float4*)(W + (size_t)n * K + skq * 4);
    else       wP[j] = make_float4(0.f, 0.f, 0.f, 0.f);
  }
#pragma unroll
  for (int j = 0; j < 2; ++j) {
    int m = sm + j * 32;
    As[0][skq * 4 + 0][m] = aP[j].x;
    As[0][skq * 4 + 1][m] = aP[j].y;
    As[0][skq * 4 + 2][m] = aP[j].z;
    As[0][skq * 4 + 3][m] = aP[j].w;
    Ws[0][skq * 4 + 0][m] = wP[j].x;
    Ws[0][skq * 4 + 1][m] = wP[j].y;
    Ws[0][skq * 4 + 2][m] = wP[j].z;
    Ws[0][skq * 4 + 3][m] = wP[j].w;
  }
  __syncthreads();
  float acc[4][4] = {{0.f}};
  int nk = K >> 5;
  for (int it = 0; it < nk; ++it) {
    int cur = it & 1, nxt = cur ^ 1;
    if (it + 1 < nk) {
      int kk = (it + 1) << 5;
#pragma unroll
      for (int j = 0; j < 2; ++j) {
        int m = sm + j * 32;
        aP[j] = *(const float4*)(A + (size_t)(m0 + m) * K + kk + skq * 4);
        int n = n0 + m;
        if (n < N) wP[j] = *(const float4*)(W + (size_t)n * K + kk + skq * 4);
        else       wP[j] = make_float4(0.f, 0.f, 0.f, 0.f);
      }
    }
#pragma unroll
    for (int k = 0; k < 32; ++k) {
      float4 a4 = *(const float4*)&As[cur][k][tr * 4];
      float4 w4 = *(const float4*)&Ws[cur][k][tc * 4];
      float a[4] = {a4.x, a4.y, a4.z, a4.w};
      float bb[4] = {w4.x, w4.y, w4.z, w4.w};
#pragma unroll
      for (int i = 0; i < 4; ++i)
#pragma unroll
        for (int j = 0; j < 4; ++j)
          acc[i][j] = fmaf(a[i], bb[j], acc[i][j]);
    }
    if (it + 1 < nk) {
#pragma unroll
      for (int j = 0; j < 2; ++j) {
        int m = sm + j * 32;
        As[nxt][skq * 4 + 0][m] = aP[j].x;
        As[nxt][skq * 4 + 1][m] = aP[j].y;
        As[nxt][skq * 4 + 2][m] = aP[j].z;
        As[nxt][skq * 4 + 3][m] = aP[j].w;
        Ws[nxt][skq * 4 + 0][m] = wP[j].x;
        Ws[nxt][skq * 4 + 1][m] = wP[j].y;
        Ws[nxt][skq * 4 + 2][m] = wP[j].z;
        Ws[nxt][skq * 4 + 3][m] = wP[j].w;
      }
      __syncthreads();
    }
  }
#pragma unroll
  for (int i = 0; i < 4; ++i) {
    int m = m0 + tr * 4 + i;
#pragma unroll
    for (int j = 0; j < 4; ++j) {
      int n = n0 + tc * 4 + j;
      if (n < N) {
        float v = acc[i][j];
        if (res) v += res[m * N + n];
        C[m * N + n] = v;
      }
    }
  }
}

// ---------------- causal depthwise conv1d(k=4) + SiLU ----------------
__global__ __launch_bounds__(256) void conv_silu(const float* __restrict__ xz,
    const float* __restrict__ cw, const float* __restrict__ cb, float* __restrict__ xc) {
  int e = blockIdx.x * 256 + threadIdx.x;
  if (e >= 4 * 1024 * 384) return;
  int d = e % 384;
  int t = (e / 384) % 1024;
  int b = e / (384 * 1024);
  const float* base = xz + (size_t)(b * 1024) * 768 + d;
  float acc = cb[d];
#pragma unroll
  for (int j = 0; j < 4; ++j) {
    int tt = t - 3 + j;
    if (tt >= 0) acc += base[(size_t)tt * 768] * cw[d * 4 + j];
  }
  float sg = 1.f / (1.f + __expf(-acc));
  xc[e] = acc * sg;
}

// ---------------- delta = softplus(dt @ dt_proj_w^T + bias) ----------------
__global__ __launch_bounds__(256) void delta_kernel(const float* __restrict__ dbc,
    const float* __restrict__ dtw, const float* __restrict__ dtb, float* __restrict__ dlt) {
  int e = blockIdx.x * 256 + threadIdx.x;
  if (e >= 4096 * 384) return;
  int d = e % 384;
  int t = e / 384;
  float s = dtb[d];
  const float* dtv = dbc + t * 140;
#pragma unroll
  for (int r = 0; r < 12; ++r) s += dtv[r] * dtw[d * 12 + r];
  dlt[e] = (s > 20.f) ? s : log1pf(__expf(s));
}

// ---------------- chunked selective scan (8 chunks x 128 steps) ----------------
__global__ __launch_bounds__(256) void scan_p1(const float* __restrict__ dlt,
    const float* __restrict__ xc, const float* __restrict__ dbc,
    const float* __restrict__ A_log, float* __restrict__ P, float* __restrict__ S) {
  int gw = (blockIdx.x * 256 + threadIdx.x) >> 6;  // [0, 12288)
  int lane = threadIdx.x & 63;
  int c  = gw & 7;
  int bd = gw >> 3;
  int b = bd / 384, d = bd % 384;
  float A = -__expf(A_log[d * 64 + lane]);
  int t0 = c * 128;
  const float* dp = dlt + ((size_t)b * 1024 + t0) * 384 + d;
  const float* xp = xc  + ((size_t)b * 1024 + t0) * 384 + d;
  const float* Bp = dbc + ((size_t)b * 1024 + t0) * 140 + 12 + lane;
  float Pv = 1.f, Sv = 0.f;
#pragma unroll 4
  for (int t = 0; t < 128; ++t) {
    float dv = dp[(size_t)t * 384];
    float xv = xp[(size_t)t * 384];
    float Bv = Bp[(size_t)t * 140];
    float a = __expf(dv * A);
    Pv *= a;
    Sv = fmaf(Sv, a, dv * xv * Bv);
  }
  size_t o = (size_t)gw * 64 + lane;   // layout [bd][c][n]
  P[o] = Pv;
  S[o] = Sv;
}

__global__ __launch_bounds__(256) void scan_p2(const float* __restrict__ P,
    const float* __restrict__ S, float* __restrict__ Hi) {
  int bd = (blockIdx.x * 256 + threadIdx.x) >> 6;  // [0, 1536)
  int lane = threadIdx.x & 63;
  size_t base = (size_t)bd * 8 * 64 + lane;
  float H = 0.f;
  Hi[base] = 0.f;
#pragma unroll
  for (int c = 1; c < 8; ++c) {
    float Pv = P[base + (size_t)(c - 1) * 64];
    float Sv = S[base + (size_t)(c - 1) * 64];
    H = fmaf(Pv, H, Sv);
    Hi[base + (size_t)c * 64] = H;
  }
}

// pass 3 with transpose-reduce: buffer 16 timesteps of h*C in LDS, then
// each lane sums a 16-element row-chunk + 2 shuffles.
__global__ __launch_bounds__(256) void scan_p3(const float* __restrict__ dlt,
    const float* __restrict__ xc, const float* __restrict__ dbc,
    const float* __restrict__ A_log, const float* __restrict__ Hi,
    float* __restrict__ y) {
  __shared__ float tile[4][16][68];
  int w = threadIdx.x >> 6;
  int gw = (blockIdx.x * 256 + threadIdx.x) >> 6;
  int lane = threadIdx.x & 63;
  int c  = gw & 7;
  int bd = gw >> 3;
  int b = bd / 384, d = bd % 384;
  float A = -__expf(A_log[d * 64 + lane]);
  int t0 = c * 128;
  const float* dp = dlt + ((size_t)b * 1024 + t0) * 384 + d;
  const float* xp = xc  + ((size_t)b * 1024 + t0) * 384 + d;
  const float* Bp = dbc + ((size_t)b * 1024 + t0) * 140 + 12 + lane;
  const float* Cp = dbc + ((size_t)b * 1024 + t0) * 140 + 76 + lane;
  float* yp = y + ((size_t)b * 1024 + t0) * 384 + d;
  float h = Hi[(size_t)gw * 64 + lane];
  int tq = lane & 15;
  int q  = lane >> 4;
  for (int tb = 0; tb < 128; tb += 16) {
#pragma unroll
    for (int tt = 0; tt < 16; ++tt) {
      int t = tb + tt;
      float dv = dp[(size_t)t * 384];
      float xv = xp[(size_t)t * 384];
      float Bv = Bp[(size_t)t * 140];
      float Cv = Cp[(size_t)t * 140];
      float a = __expf(dv * A);
      h = fmaf(h, a, dv * xv * Bv);
      tile[w][tt][lane] = h * Cv;
    }
    const float* trow = &tile[w][tq][q * 16];
    float s = 0.f;
#pragma unroll
    for (int i = 0; i < 16; ++i) s += trow[i];
    s += __shfl_xor(s, 16, 64);
    s += __shfl_xor(s, 32, 64);
    if (lane < 16) yp[(size_t)(tb + lane) * 384] = s;
  }
}

// ---------------- gating: yg = (y + xc*D) * silu(z) ----------------
__global__ __launch_bounds__(256) void gate_kernel(float* __restrict__ y,
    const float* __restrict__ xc, const float* __restrict__ xz,
    const float* __restrict__ D, float* __restrict__ yg) {
  int e = blockIdx.x * 256 + threadIdx.x;
  if (e >= 4096 * 384) return;
  int d = e % 384;
  int row = e / 384;
  float zv = xz[(size_t)row * 768 + 384 + d];
  float sg = zv / (1.f + __expf(-zv));
  yg[e] = (y[e] + xc[e] * D[d]) * sg;
}

// ---------------- single-column 1024-pt radix-2 FFT in LDS ----------------
__device__ __forceinline__ void fft1024c(float* __restrict__ re,
    float* __restrict__ im, int tid, float sgn) {
  for (int i = tid; i < 1024; i += 256) {
    int r = (int)(__brev((unsigned)i) >> 22);
    if (i < r) {
      float tr = re[i]; re[i] = re[r]; re[r] = tr;
      float ti = im[i]; im[i] = im[r]; im[r] = ti;
    }
  }
  __syncthreads();
  for (int s = 0; s < 10; ++s) {
    int half = 1 << s;
#pragma unroll
    for (int uu = 0; uu < 2; ++uu) {
      int u = tid + uu * 256;
      int j = u & (half - 1);
      int i0 = ((u >> s) << (s + 1)) + j;
      int i1 = i0 + half;
      float ang = sgn * PI_F * (float)j / (float)half;
      float sw, cw;
      __sincosf(ang, &sw, &cw);
      float br = re[i1], bi = im[i1];
      float tr = br * cw - bi * sw;
      float ti = br * sw + bi * cw;
      float ar = re[i0], ai = im[i0];
      re[i1] = ar - tr; im[i1] = ai - ti;
      re[i0] = ar + tr; im[i0] = ai + ti;
    }
    __syncthreads();
  }
}

// forward fft2: one block per (Bi,d,c). Inline 4-pt DFT over c on load.
__global__ __launch_bounds__(256) void fft_fwd(const float* __restrict__ xin,
    float* __restrict__ Xre, float* __restrict__ Xim) {
  __shared__ float re[1024];
  __shared__ float im[1024];
  int blk = blockIdx.x;
  int c = blk & 3;
  int rest = blk >> 2;
  int d = rest % 48, Bi = rest / 48;
  int tid = threadIdx.x;
  for (int n = tid; n < 1024; n += 256) {
    const float* p = xin + (size_t)(Bi * 1024 + n) * 192 + d;
    float v0 = p[0], v1 = p[48], v2 = p[96], v3 = p[144];
    float rr, ii;
    if (c == 0)      { rr = v0 + v1 + v2 + v3; ii = 0.f; }
    else if (c == 1) { rr = v0 - v2;           ii = -(v1 - v3); }
    else if (c == 2) { rr = v0 - v1 + v2 - v3; ii = 0.f; }
    else             { rr = v0 - v2;           ii = (v1 - v3); }
    re[n] = rr; im[n] = ii;
  }
  __syncthreads();
  fft1024c(re, im, tid, -1.0f);
  for (int k = tid; k < 1024; k += 256) {
    size_t o = ((size_t)(Bi * 1024 + k) * 4 + c) * 48 + d;
    Xre[o] = re[k] * (1.f / 64.f);
    Xim[o] = im[k] * (1.f / 64.f);
  }
}

// ---------------- EinFFT frequency mix, layer 1: one thread per (row, j) ----
__global__ __launch_bounds__(256) void mix_l1(const float* __restrict__ Xre,
    const float* __restrict__ Xim, const float* __restrict__ cw1,
    const float* __restrict__ cb1, float* __restrict__ r1, float* __restrict__ i1) {
  int e = blockIdx.x * 256 + threadIdx.x;   // [0, 786432)
  int j = e % 48;
  int row = e / 48;
  int b = row & 3;
  const float* wr = cw1 + b * 2304;
  const float* wi = cw1 + 9216 + b * 2304;
  const float* xr = Xre + (size_t)row * 48;
  const float* xi = Xim + (size_t)row * 48;
  float ar = cb1[b * 48 + j];
  float ai = cb1[192 + b * 48 + j];
#pragma unroll 12
  for (int dd = 0; dd < 48; ++dd) {
    float xrv = xr[dd], xiv = xi[dd];
    float wrv = wr[dd * 48 + j], wiv = wi[dd * 48 + j];
    ar = fmaf(xrv, wrv, ar);
    ar = fmaf(-xiv, wiv, ar);
    ai = fmaf(xrv, wiv, ai);
    ai = fmaf(xiv, wrv, ai);
  }
  r1[e] = fmaxf(ar, 0.f);
  i1[e] = fmaxf(ai, 0.f);
}

// layer 2 + softshrink, writes Z in-place over X
__global__ __launch_bounds__(256) void mix_l2(const float* __restrict__ r1,
    const float* __restrict__ i1, const float* __restrict__ cw2,
    const float* __restrict__ cb2, float* __restrict__ Xre, float* __restrict__ Xim) {
  int e = blockIdx.x * 256 + threadIdx.x;
  int j = e % 48;
  int row = e / 48;
  int b = row & 3;
  const float* wr = cw2 + b * 2304;
  const float* wi = cw2 + 9216 + b * 2304;
  const float* rr = r1 + (size_t)row * 48;
  const float* ri = i1 + (size_t)row * 48;
  float ar = cb2[b * 48 + j];
  float ai = cb2[192 + b * 48 + j];
#pragma unroll 12
  for (int dd = 0; dd < 48; ++dd) {
    float rv = rr[dd], iv = ri[dd];
    float wrv = wr[dd * 48 + j], wiv = wi[dd * 48 + j];
    ar = fmaf(rv, wrv, ar);
    ar = fmaf(-iv, wiv, ar);
    ai = fmaf(rv, wiv, ai);
    ai = fmaf(iv, wrv, ai);
  }
  float zr = (ar > 0.01f) ? ar - 0.01f : ((ar < -0.01f) ? ar + 0.01f : 0.f);
  float zi = (ai > 0.01f) ? ai - 0.01f : ((ai < -0.01f) ? ai + 0.01f : 0.f);
  Xre[e] = zr;
  Xim[e] = zi;
}

// inverse fft2: one block per (Bi,d,c). Inline inverse 4-pt DFT on load,
// IFFT, add residual, write real part.
__global__ __launch_bounds__(256) void fft_inv(const float* __restrict__ Zre,
    const float* __restrict__ Zim, const float* __restrict__ x1, float* __restrict__ out) {
  __shared__ float re[1024];
  __shared__ float im[1024];
  int blk = blockIdx.x;
  int c = blk & 3;
  int rest = blk >> 2;
  int d = rest % 48, Bi = rest / 48;
  int tid = threadIdx.x;
  for (int k = tid; k < 1024; k += 256) {
    size_t o = ((size_t)(Bi * 1024 + k) * 4) * 48 + d;
    float r0 = Zre[o], r1v = Zre[o + 48], r2 = Zre[o + 96], r3 = Zre[o + 144];
    float i0 = Zim[o], i1v = Zim[o + 48], i2 = Zim[o + 96], i3 = Zim[o + 144];
    float rr, ii;
    if (c == 0)      { rr = r0 + r1v + r2 + r3;  ii = i0 + i1v + i2 + i3; }
    else if (c == 1) { rr = r0 - i1v - r2 + i3;  ii = i0 + r1v - i2 - r3; }
    else if (c == 2) { rr = r0 - r1v + r2 - r3;  ii = i0 - i1v + i2 - i3; }
    else             { rr = r0 + i1v - r2 - i3;  ii = i0 - r1v - i2 + r3; }
    re[k] = rr; im[k] = ii;
  }
  __syncthreads();
  fft1024c(re, im, tid, 1.0f);
  for (int n = tid; n < 1024; n += 256) {
    size_t o = (size_t)(Bi * 1024 + n) * 192 + c * 48 + d;
    out[o] = x1[o] + re[n] * (1.f / 64.f);
  }
}

extern "C" void kernel_launch(void* const* d_in, const int* in_sizes, int n_in,
                              void* d_out, int out_size, void* d_ws, size_t ws_size,
                              hipStream_t stream) {
  const float* x         = (const float*)d_in[0];
  const float* ln1_w     = (const float*)d_in[1];
  const float* ln1_b     = (const float*)d_in[2];
  const float* in_proj_w = (const float*)d_in[3];
  const float* conv_w    = (const float*)d_in[4];
  const float* conv_b    = (const float*)d_in[5];
  const float* x_proj_w  = (const float*)d_in[6];
  const float* dt_proj_w = (const float*)d_in[7];
  const float* dt_proj_b = (const float*)d_in[8];
  const float* A_log     = (const float*)d_in[9];
  const float* Dvec      = (const float*)d_in[10];
  const float* out_proj_w= (const float*)d_in[11];
  const float* ln2_w     = (const float*)d_in[12];
  const float* ln2_b     = (const float*)d_in[13];
  const float* cw1       = (const float*)d_in[14];
  const float* cw2       = (const float*)d_in[15];
  const float* cb1       = (const float*)d_in[16];
  const float* cb2       = (const float*)d_in[17];
  float* out = (float*)d_out;
  float* ws  = (float*)d_ws;

  // workspace layout (floats); aliases:
  //  P/S/Hi (scan summaries) alias x2/Xre/Xim (dead until after scan)
  //  r1/i1 (einfft layer-1 out) alias dlt/yv (dead after scan/out_proj)
  float* xln = ws;                       // 786432
  float* xz  = xln + 786432;             // 3145728
  float* xc  = xz  + 3145728;            // 1572864
  float* dbc = xc  + 1572864;            // 573440
  float* dlt = dbc + 573440;             // 1572864
  float* yv  = dlt + 1572864;            // 1572864
  float* x2  = yv  + 1572864;            // 786432
  float* Xre = x2  + 786432;             // 786432
  float* Xim = Xre + 786432;             // 786432
  float* Pb = x2;    // scan pass-1 products
  float* Sb = Xre;   // scan pass-1 partials
  float* Hi = Xim;   // per-chunk h_init
  float* r1 = dlt;   // einfft layer-1 real
  float* i1 = yv;    // einfft layer-1 imag

  ln_kernel<<<4096, 64, 0, stream>>>(x, ln1_w, ln1_b, xln);
  gemm_tn<<<dim3(12, 64), 256, 0, stream>>>(xln, in_proj_w, nullptr, xz, 4096, 768, 192);
  conv_silu<<<6144, 256, 0, stream>>>(xz, conv_w, conv_b, xc);
  gemm_tn<<<dim3(3, 64), 256, 0, stream>>>(xc, x_proj_w, nullptr, dbc, 4096, 140, 384);
  delta_kernel<<<6144, 256, 0, stream>>>(dbc, dt_proj_w, dt_proj_b, dlt);
  scan_p1<<<3072, 256, 0, stream>>>(dlt, xc, dbc, A_log, Pb, Sb);
  scan_p2<<<384, 256, 0, stream>>>(Pb, Sb, Hi);
  scan_p3<<<3072, 256, 0, stream>>>(dlt, xc, dbc, A_log, Hi, yv);
  gate_kernel<<<6144, 256, 0, stream>>>(yv, xc, xz, Dvec, yv);
  float* x1 = xln;
  gemm_tn<<<dim3(3, 64), 256, 0, stream>>>(yv, out_proj_w, x, x1, 4096, 192, 384);
  ln_kernel<<<4096, 64, 0, stream>>>(x1, ln2_w, ln2_b, x2);
  fft_fwd<<<768, 256, 0, stream>>>(x2, Xre, Xim);
  mix_l1<<<3072, 256, 0, stream>>>(Xre, Xim, cw1, cb1, r1, i1);
  mix_l2<<<3072, 256, 0, stream>>>(r1, i1, cw2, cb2, Xre, Xim);
  fft_inv<<<768, 256, 0, stream>>>(Xre, Xim, x1, out);
}